// Round 1
// baseline (263.313 us; speedup 1.0000x reference)
//
#include <hip/hip_runtime.h>
#include <hip/hip_bf16.h>

// Shapes (fixed): B=8, E=768, C=256, CI=128, H=W=14, UP=4 -> H2=W2=56, N=3136, NQ=196
#define B_ 8
#define E_ 768
#define C_ 256
#define CI_ 128
#define NQ_ 196
#define N_ 3136

// ---------------- K1: FCUUp proj+BN+ReLU fused with phi projection -------------
// grid: B * 25 (q-tiles of 8, tail 4), block 256
__global__ __launch_bounds__(256) void k1_fcuup_phi(
    const float* __restrict__ x_t, const float* __restrict__ Wp, const float* __restrict__ bp,
    const float* __restrict__ g1, const float* __restrict__ b1,
    const float* __restrict__ rm1, const float* __restrict__ rv1,
    const float* __restrict__ Wph, const float* __restrict__ bph,
    float* __restrict__ phi_ws)
{
    __shared__ float xrow[8][768];   // 24KB
    __shared__ float xact[8][256];   // 8KB
    int bx = blockIdx.x;
    int b = bx / 25, qt = bx % 25;
    int q0 = qt * 8;
    int t = threadIdx.x;

    // stage 8 token rows (768 floats each) -> 1536 float4, 6 per thread
    #pragma unroll
    for (int rr = 0; rr < 6; ++rr) {
        int idx = t + rr * 256;          // 0..1535
        int p = idx / 192;               // 192 float4 per row
        int e4 = idx % 192;
        int q = q0 + p;
        if (q < NQ_) {
            float4 v = *(const float4*)(x_t + (size_t)b * 197 * 768 + (size_t)(1 + q) * 768 + e4 * 4);
            *(float4*)(&xrow[p][e4 * 4]) = v;
        }
    }
    __syncthreads();

    // proj: one output channel per thread, 8 pixels
    int c = t;
    float acc[8] = {0, 0, 0, 0, 0, 0, 0, 0};
    const float* wrow = Wp + (size_t)c * 768;
    for (int e4 = 0; e4 < 192; ++e4) {
        float4 w = *(const float4*)(wrow + e4 * 4);
        #pragma unroll
        for (int p = 0; p < 8; ++p) {
            float4 xv = *(const float4*)(&xrow[p][e4 * 4]);
            acc[p] += w.x * xv.x + w.y * xv.y + w.z * xv.z + w.w * xv.w;
        }
    }
    float inv1 = g1[c] * rsqrtf(rv1[c] + 1e-6f);
    float add1 = b1[c] - rm1[c] * inv1;
    float bpc = bp[c];
    #pragma unroll
    for (int p = 0; p < 8; ++p) {
        float v = (acc[p] + bpc) * inv1 + add1;
        xact[p][c] = fmaxf(v, 0.0f);
    }
    __syncthreads();

    // phi: 128 i x 8 p ; thread: i = t&127, grp = t>>7 handles 4 pixels
    int i = t & 127, grp = t >> 7;
    float pacc[4] = {0, 0, 0, 0};
    const float* wphrow = Wph + (size_t)i * 256;
    for (int c4 = 0; c4 < 64; ++c4) {
        float4 w = *(const float4*)(wphrow + c4 * 4);
        #pragma unroll
        for (int pp = 0; pp < 4; ++pp) {
            int p = grp * 4 + pp;
            float4 xv = *(const float4*)(&xact[p][c4 * 4]);
            pacc[pp] += w.x * xv.x + w.y * xv.y + w.z * xv.z + w.w * xv.w;
        }
    }
    float bphi = bph[i];
    #pragma unroll
    for (int pp = 0; pp < 4; ++pp) {
        int q = q0 + grp * 4 + pp;
        if (q < NQ_)
            phi_ws[(size_t)b * CI_ * NQ_ + (size_t)i * NQ_ + q] = pacc[pp] + bphi;
    }
}

// ---------------- K2: theta + g GEMM (256 out rows = [theta;g], K=256) ----------
// grid: B * 4 * 49 = 1568, block 256. Tile: 64 rows x 64 cols, KC=32.
__global__ __launch_bounds__(256) void k2_theta_g(
    const float* __restrict__ x_cnn,
    const float* __restrict__ Wth, const float* __restrict__ bth,
    const float* __restrict__ Wg, const float* __restrict__ bg,
    float* __restrict__ theta_ws, float* __restrict__ g_ws)
{
    __shared__ float Xs[32][64];     // 8KB
    __shared__ float WsT[32][68];    // 8.5KB (pad 4 -> 16B-aligned rows, spread banks)
    int bx = blockIdx.x;
    int b = bx / 196;
    int r = bx % 196;
    int it = r / 49;                 // 0..3
    int nt = r % 49;                 // 0..48
    int i0 = it * 64, n0 = nt * 64;
    int t = threadIdx.x;
    int ti = t >> 4, tn = t & 15;    // 16x16 thread grid, 4x4 microtile

    float acc[4][4] = {};
    const float* xb = x_cnn + (size_t)b * C_ * N_;

    for (int k0 = 0; k0 < 256; k0 += 32) {
        // stage X tile [32 k][64 n] : 512 float4, 2 per thread
        #pragma unroll
        for (int rr = 0; rr < 2; ++rr) {
            int idx = t + rr * 256;       // 0..511
            int k = idx >> 4;
            int n4 = idx & 15;
            float4 xv = *(const float4*)(xb + (size_t)(k0 + k) * N_ + n0 + n4 * 4);
            *(float4*)(&Xs[k][n4 * 4]) = xv;
        }
        // stage W transposed [32 k][64 i]
        #pragma unroll
        for (int rr = 0; rr < 2; ++rr) {
            int idx = t + rr * 256;
            int i = idx >> 3;             // 0..63
            int k4 = idx & 7;
            int gi = i0 + i;
            const float* wr = (gi < 128) ? (Wth + (size_t)gi * 256)
                                         : (Wg + (size_t)(gi - 128) * 256);
            float4 wv = *(const float4*)(wr + k0 + k4 * 4);
            WsT[k4 * 4 + 0][i] = wv.x;
            WsT[k4 * 4 + 1][i] = wv.y;
            WsT[k4 * 4 + 2][i] = wv.z;
            WsT[k4 * 4 + 3][i] = wv.w;
        }
        __syncthreads();
        for (int k = 0; k < 32; ++k) {
            float4 a = *(const float4*)(&WsT[k][ti * 4]);
            float4 bv = *(const float4*)(&Xs[k][tn * 4]);
            float av[4] = {a.x, a.y, a.z, a.w};
            float bvv[4] = {bv.x, bv.y, bv.z, bv.w};
            #pragma unroll
            for (int ii = 0; ii < 4; ++ii)
                #pragma unroll
                for (int jj = 0; jj < 4; ++jj)
                    acc[ii][jj] += av[ii] * bvv[jj];
        }
        __syncthreads();
    }

    if (i0 < 128) {
        // theta rows: layout [b][i][n]
        #pragma unroll
        for (int ii = 0; ii < 4; ++ii) {
            int gi = i0 + ti * 4 + ii;
            float bias = bth[gi];
            float4 v = make_float4(acc[ii][0] + bias, acc[ii][1] + bias,
                                   acc[ii][2] + bias, acc[ii][3] + bias);
            *(float4*)(theta_ws + (size_t)b * CI_ * N_ + (size_t)gi * N_ + n0 + tn * 4) = v;
        }
    } else {
        // g rows: transposed layout [b][n][i]
        #pragma unroll
        for (int ii = 0; ii < 4; ++ii) {
            int gi = i0 - 128 + ti * 4 + ii;
            float bias = bg[gi];
            #pragma unroll
            for (int jj = 0; jj < 4; ++jj) {
                int n = n0 + tn * 4 + jj;
                g_ws[(size_t)b * N_ * CI_ + (size_t)n * CI_ + gi] = acc[ii][jj] + bias;
            }
        }
    }
}

// ---------------- K3: attention (196 unique queries/batch) ---------------------
// grid: 8*49 = 392 (b = blockIdx%8 for XCD L2 affinity), block 256, 4 queries/block
__global__ __launch_bounds__(256) void k3_attn(
    const float* __restrict__ phi_ws, const float* __restrict__ theta_ws,
    const float* __restrict__ g_ws, float* __restrict__ y_ws)
{
    __shared__ float phi_s[128][4];     // [i][q], 2KB
    __shared__ float f_lds[4][3136];    // 50.2KB
    __shared__ float red[2][4][4];      // [phase][q][wave]
    __shared__ float ypart[2][4][128];  // 4KB
    int bx = blockIdx.x;
    int b = bx & 7, qt = bx >> 3;
    int q0 = qt * 4;
    int t = threadIdx.x;

    for (int idx = t; idx < 512; idx += 256) {
        int q = idx >> 7, i = idx & 127;
        phi_s[i][q] = phi_ws[(size_t)b * CI_ * NQ_ + (size_t)i * NQ_ + q0 + q];
    }
    __syncthreads();

    const float* thb = theta_ws + (size_t)b * CI_ * N_;
    float lmax[4] = {-1e30f, -1e30f, -1e30f, -1e30f};

    // pass 1: f[q][n] = sum_i phi[i][q]*theta[i][n], thread handles float4 n-chunks
    for (int n4 = t; n4 < 784; n4 += 256) {
        int n = n4 * 4;
        float fq[4][4] = {};
        for (int i = 0; i < 128; ++i) {
            float4 th = *(const float4*)(thb + (size_t)i * N_ + n);
            float4 ph = *(const float4*)(&phi_s[i][0]);
            float thv[4] = {th.x, th.y, th.z, th.w};
            float phv[4] = {ph.x, ph.y, ph.z, ph.w};
            #pragma unroll
            for (int q = 0; q < 4; ++q)
                #pragma unroll
                for (int d = 0; d < 4; ++d)
                    fq[q][d] += phv[q] * thv[d];
        }
        #pragma unroll
        for (int q = 0; q < 4; ++q) {
            #pragma unroll
            for (int d = 0; d < 4; ++d) lmax[q] = fmaxf(lmax[q], fq[q][d]);
            *(float4*)(&f_lds[q][n]) = make_float4(fq[q][0], fq[q][1], fq[q][2], fq[q][3]);
        }
    }

    // block-wide max per q
    #pragma unroll
    for (int q = 0; q < 4; ++q) {
        float m = lmax[q];
        for (int off = 32; off >= 1; off >>= 1) m = fmaxf(m, __shfl_xor(m, off));
        if ((t & 63) == 0) red[0][q][t >> 6] = m;
    }
    __syncthreads();
    float rmax[4];
    #pragma unroll
    for (int q = 0; q < 4; ++q)
        rmax[q] = fmaxf(fmaxf(red[0][q][0], red[0][q][1]), fmaxf(red[0][q][2], red[0][q][3]));

    // exp + local sums (threads touch only their own f_lds slots)
    float lsum[4] = {0, 0, 0, 0};
    for (int n4 = t; n4 < 784; n4 += 256) {
        int n = n4 * 4;
        #pragma unroll
        for (int q = 0; q < 4; ++q) {
            float4 v = *(const float4*)(&f_lds[q][n]);
            float e0 = __expf(v.x - rmax[q]);
            float e1 = __expf(v.y - rmax[q]);
            float e2 = __expf(v.z - rmax[q]);
            float e3 = __expf(v.w - rmax[q]);
            lsum[q] += (e0 + e1) + (e2 + e3);
            *(float4*)(&f_lds[q][n]) = make_float4(e0, e1, e2, e3);
        }
    }
    #pragma unroll
    for (int q = 0; q < 4; ++q) {
        float s = lsum[q];
        for (int off = 32; off >= 1; off >>= 1) s += __shfl_xor(s, off);
        if ((t & 63) == 0) red[1][q][t >> 6] = s;
    }
    __syncthreads();   // also orders exp write-back before pass 3
    float inv[4];
    #pragma unroll
    for (int q = 0; q < 4; ++q)
        inv[q] = 1.0f / (((red[1][q][0] + red[1][q][1]) + (red[1][q][2] + red[1][q][3])));

    // pass 3: y[q][i] = sum_n p[q][n]*g[n][i]
    int i = t & 127, half = t >> 7;
    const float* gb = g_ws + (size_t)b * N_ * CI_;
    float y[4] = {0, 0, 0, 0};
    int nbeg = half * 1568, nend = nbeg + 1568;
    for (int n = nbeg; n < nend; ++n) {
        float gv = gb[(size_t)n * CI_ + i];
        #pragma unroll
        for (int q = 0; q < 4; ++q) y[q] += f_lds[q][n] * gv;
    }
    #pragma unroll
    for (int q = 0; q < 4; ++q) ypart[half][q][i] = y[q];
    __syncthreads();
    for (int idx = t; idx < 512; idx += 256) {
        int q = idx >> 7, ii = idx & 127;
        float val = (ypart[0][q][ii] + ypart[1][q][ii]) * inv[q];
        y_ws[(size_t)b * NQ_ * CI_ + (size_t)(q0 + q) * CI_ + ii] = val;
    }
}

// ---------------- K4a: z = BN2(Wz @ y + bz) on 196-grid -------------------------
// grid: B*25, block 256
__global__ __launch_bounds__(256) void k4a_z(
    const float* __restrict__ y_ws, const float* __restrict__ Wz, const float* __restrict__ bz,
    const float* __restrict__ g2, const float* __restrict__ b2,
    const float* __restrict__ rm2, const float* __restrict__ rv2,
    float* __restrict__ z_ws)
{
    __shared__ float ys[8][128];
    int bx = blockIdx.x;
    int b = bx / 25, qt = bx % 25;
    int q0 = qt * 8;
    int t = threadIdx.x;
    #pragma unroll
    for (int rr = 0; rr < 4; ++rr) {
        int idx = t + rr * 256;          // 0..1023
        int p = idx >> 7, ii = idx & 127;
        int q = q0 + p;
        ys[p][ii] = (q < NQ_) ? y_ws[(size_t)b * NQ_ * CI_ + (size_t)q * CI_ + ii] : 0.0f;
    }
    __syncthreads();
    int c = t;
    float acc[8] = {0, 0, 0, 0, 0, 0, 0, 0};
    const float* wrow = Wz + (size_t)c * 128;
    for (int i4 = 0; i4 < 32; ++i4) {
        float4 w = *(const float4*)(wrow + i4 * 4);
        #pragma unroll
        for (int p = 0; p < 8; ++p) {
            float4 yv = *(const float4*)(&ys[p][i4 * 4]);
            acc[p] += w.x * yv.x + w.y * yv.y + w.z * yv.z + w.w * yv.w;
        }
    }
    float inv2 = g2[c] * rsqrtf(rv2[c] + 1e-5f);
    float add2 = b2[c] - rm2[c] * inv2;
    float bzc = bz[c];
    #pragma unroll
    for (int p = 0; p < 8; ++p) {
        int q = q0 + p;
        if (q < NQ_)
            z_ws[(size_t)b * C_ * NQ_ + (size_t)c * NQ_ + q] = (acc[p] + bzc) * inv2 + add2;
    }
}

// ---------------- K4b: out = upsample(z) + x_cnn --------------------------------
// grid: 6272, block 256, one float4 per thread
__global__ __launch_bounds__(256) void k4b_out(
    const float* __restrict__ x_cnn, const float* __restrict__ z_ws, float* __restrict__ out)
{
    int idx = blockIdx.x * 256 + threadIdx.x;   // float4 index over (B,C,56,14)
    int w4 = idx % 14;
    int rest = idx / 14;
    int h = rest % 56;
    rest /= 56;
    int c = rest % 256;
    int b = rest / 256;
    int q = (h >> 2) * 14 + w4;
    float z = z_ws[((size_t)b * C_ + c) * NQ_ + q];
    float4 xv = *(const float4*)(x_cnn + (size_t)idx * 4);
    float4 o = make_float4(xv.x + z, xv.y + z, xv.z + z, xv.w + z);
    *(float4*)(out + (size_t)idx * 4) = o;
}

extern "C" void kernel_launch(void* const* d_in, const int* in_sizes, int n_in,
                              void* d_out, int out_size, void* d_ws, size_t ws_size,
                              hipStream_t stream) {
    const float* x_t   = (const float*)d_in[0];
    const float* x_cnn = (const float*)d_in[1];
    const float* Wp  = (const float*)d_in[2];
    const float* bp  = (const float*)d_in[3];
    const float* g1  = (const float*)d_in[4];
    const float* b1  = (const float*)d_in[5];
    const float* rm1 = (const float*)d_in[6];
    const float* rv1 = (const float*)d_in[7];
    const float* Wg  = (const float*)d_in[8];
    const float* bg  = (const float*)d_in[9];
    const float* Wth = (const float*)d_in[10];
    const float* bth = (const float*)d_in[11];
    const float* Wph = (const float*)d_in[12];
    const float* bph = (const float*)d_in[13];
    const float* Wz  = (const float*)d_in[14];
    const float* bz  = (const float*)d_in[15];
    const float* g2  = (const float*)d_in[16];
    const float* b2  = (const float*)d_in[17];
    const float* rm2 = (const float*)d_in[18];
    const float* rv2 = (const float*)d_in[19];
    float* out = (float*)d_out;

    char* ws = (char*)d_ws;
    float* theta_ws = (float*)(ws);                  // 8*128*3136*4 = 12,845,056
    float* g_ws     = (float*)(ws + 12845056);       // 12,845,056
    float* phi_ws   = (float*)(ws + 25690112);       // 8*128*196*4 = 802,816
    float* y_ws     = (float*)(ws + 26492928);       // 802,816
    float* z_ws     = (float*)(ws + 27295744);       // 8*256*196*4 = 1,605,632

    k1_fcuup_phi<<<dim3(200), dim3(256), 0, stream>>>(x_t, Wp, bp, g1, b1, rm1, rv1, Wph, bph, phi_ws);
    k2_theta_g<<<dim3(1568), dim3(256), 0, stream>>>(x_cnn, Wth, bth, Wg, bg, theta_ws, g_ws);
    k3_attn<<<dim3(392), dim3(256), 0, stream>>>(phi_ws, theta_ws, g_ws, y_ws);
    k4a_z<<<dim3(200), dim3(256), 0, stream>>>(y_ws, Wz, bz, g2, b2, rm2, rv2, z_ws);
    k4b_out<<<dim3(6272), dim3(256), 0, stream>>>(x_cnn, z_ws, out);
}

// Round 2
// 143.006 us; speedup vs baseline: 1.8413x; 1.8413x over previous
//
#include <hip/hip_runtime.h>
#include <hip/hip_bf16.h>

// Shapes (fixed): B=8, E=768, C=256, CI=128, H=W=14, UP=4 -> H2=W2=56, N=3136, NQ=196
#define B_ 8
#define E_ 768
#define C_ 256
#define CI_ 128
#define NQ_ 196
#define N_ 3136

typedef short bf16x8 __attribute__((ext_vector_type(8)));
typedef float f32x4 __attribute__((ext_vector_type(4)));

__device__ __forceinline__ ushort f2bf(float x) {
    union { float f; uint u; } v; v.f = x;
    uint r = v.u + 0x7FFFu + ((v.u >> 16) & 1u);   // RNE
    return (ushort)(r >> 16);
}
__device__ __forceinline__ uint pack2(float a, float b) {
    return (uint)f2bf(a) | ((uint)f2bf(b) << 16);
}

// ---------------- kconv: weights -> bf16, zero y accumulator -------------------
// grid 256, block 256
__global__ __launch_bounds__(256) void kconv_w(
    const float* __restrict__ Wth, const float* __restrict__ Wg,
    ushort* __restrict__ Wcomb, float* __restrict__ y_ws)
{
    int idx = blockIdx.x * 256 + threadIdx.x;     // 0..65535
    int o = idx >> 8, c = idx & 255;
    float v = (o < 128) ? Wth[o * 256 + c] : Wg[(o - 128) * 256 + c];
    Wcomb[idx] = f2bf(v);
    for (int i = idx; i < B_ * NQ_ * CI_; i += 65536) y_ws[i] = 0.0f;
}

// ---------------- k0: x_cnn [b][c][n] fp32 -> xT [b][n][c] bf16 ----------------
// grid 8*4*49 = 1568, block 256
__global__ __launch_bounds__(256) void k0_xT(
    const float* __restrict__ x_cnn, ushort* __restrict__ xT)
{
    __shared__ float Xs[64][68];
    int bx = blockIdx.x;
    int b = bx & 7; int rest = bx >> 3;
    int ct = rest & 3, nt = rest >> 2;            // ct 0..3, nt 0..48
    int c0 = ct * 64, n0 = nt * 64;
    int t = threadIdx.x;
    #pragma unroll
    for (int rr = 0; rr < 4; ++rr) {
        int idx = t + rr * 256;                   // 0..1023
        int c = idx >> 4, n4 = idx & 15;
        float4 v = *(const float4*)(x_cnn + ((size_t)(b * C_) + c0 + c) * N_ + n0 + n4 * 4);
        *(float4*)(&Xs[c][n4 * 4]) = v;
    }
    __syncthreads();
    int n = t & 63, cc = t >> 6;                  // cc 0..3 (16 c each)
    ushort vals[16];
    #pragma unroll
    for (int j = 0; j < 16; ++j)
        vals[j] = f2bf(Xs[cc * 16 + j][n]);
    ushort* outp = xT + ((size_t)(b * N_) + n0 + n) * 256 + c0 + cc * 16;
    *(uint4*)(outp) = *(const uint4*)(&vals[0]);
    *(uint4*)(outp + 8) = *(const uint4*)(&vals[8]);
}

// ---------------- K1: FCUUp proj+BN+ReLU fused with phi projection -------------
// grid: 8*32 = 256 (q-tiles of 8, padded to 256 rows), block 256
__global__ __launch_bounds__(256) void k1_fcuup_phi(
    const float* __restrict__ x_t, const float* __restrict__ Wp, const float* __restrict__ bp,
    const float* __restrict__ g1, const float* __restrict__ b1,
    const float* __restrict__ rm1, const float* __restrict__ rv1,
    const float* __restrict__ Wph, const float* __restrict__ bph,
    ushort* __restrict__ phi_bf)
{
    __shared__ float xrow[8][768];   // 24KB
    __shared__ float xact[8][256];   // 8KB
    int bx = blockIdx.x;
    int b = bx >> 5, qt = bx & 31;
    int q0 = qt * 8;
    int t = threadIdx.x;

    #pragma unroll
    for (int rr = 0; rr < 6; ++rr) {
        int idx = t + rr * 256;          // 0..1535
        int p = idx / 192;
        int e4 = idx % 192;
        int q = q0 + p;
        if (q < NQ_) {
            float4 v = *(const float4*)(x_t + (size_t)b * 197 * 768 + (size_t)(1 + q) * 768 + e4 * 4);
            *(float4*)(&xrow[p][e4 * 4]) = v;
        }
    }
    __syncthreads();

    int c = t;
    float acc[8] = {0, 0, 0, 0, 0, 0, 0, 0};
    const float* wrow = Wp + (size_t)c * 768;
    for (int e4 = 0; e4 < 192; ++e4) {
        float4 w = *(const float4*)(wrow + e4 * 4);
        #pragma unroll
        for (int p = 0; p < 8; ++p) {
            float4 xv = *(const float4*)(&xrow[p][e4 * 4]);
            acc[p] += w.x * xv.x + w.y * xv.y + w.z * xv.z + w.w * xv.w;
        }
    }
    float inv1 = g1[c] * rsqrtf(rv1[c] + 1e-6f);
    float add1 = b1[c] - rm1[c] * inv1;
    float bpc = bp[c];
    #pragma unroll
    for (int p = 0; p < 8; ++p) {
        float v = (acc[p] + bpc) * inv1 + add1;
        xact[p][c] = fmaxf(v, 0.0f);
    }
    __syncthreads();

    int i = t & 127, grp = t >> 7;
    float pacc[4] = {0, 0, 0, 0};
    const float* wphrow = Wph + (size_t)i * 256;
    for (int c4 = 0; c4 < 64; ++c4) {
        float4 w = *(const float4*)(wphrow + c4 * 4);
        #pragma unroll
        for (int pp = 0; pp < 4; ++pp) {
            int p = grp * 4 + pp;
            float4 xv = *(const float4*)(&xact[p][c4 * 4]);
            pacc[pp] += w.x * xv.x + w.y * xv.y + w.z * xv.z + w.w * xv.w;
        }
    }
    float bphi = bph[i];
    #pragma unroll
    for (int pp = 0; pp < 4; ++pp) {
        int q = q0 + grp * 4 + pp;
        ushort val = (q < NQ_) ? f2bf(pacc[pp] + bphi) : (ushort)0;
        phi_bf[((size_t)((b << 8) + q)) * 128 + i] = val;
    }
}

// ---------------- K2: MFMA GEMM out[o][n] = Wcomb[o]·xT[n], K=256 --------------
// grid 8*4*49 = 1568 (b = bx&7), block 256 (4 waves, 64x64 tile)
__global__ __launch_bounds__(256) void k2_mfma(
    const ushort* __restrict__ Wcomb, const float* __restrict__ bth, const float* __restrict__ bg,
    const ushort* __restrict__ xT, ushort* __restrict__ thT, ushort* __restrict__ gT)
{
    __shared__ ushort Al[64 * 40];   // rows padded to 80B
    __shared__ ushort Bl[64 * 40];
    int bx = blockIdx.x;
    int b = bx & 7; int rest = bx >> 3;
    int mt = rest & 3, nt = rest >> 2;
    int o0 = mt * 64, n0 = nt * 64;
    int t = threadIdx.x;
    int lane = t & 63, w = t >> 6;
    int wm = w >> 1, wn = w & 1;
    int row = t >> 2, chunk = t & 3;

    const ushort* ga = Wcomb + (size_t)(o0 + row) * 256 + chunk * 8;
    const ushort* gb = xT + ((size_t)(b * N_) + n0 + row) * 256 + chunk * 8;
    ushort* la = &Al[row * 40 + chunk * 8];
    ushort* lb = &Bl[row * 40 + chunk * 8];

    f32x4 acc[2][2];
    #pragma unroll
    for (int a = 0; a < 2; ++a)
        #pragma unroll
        for (int bb = 0; bb < 2; ++bb) acc[a][bb] = (f32x4){0.f, 0.f, 0.f, 0.f};

    int am = (wm * 32 + (lane & 15)) * 40 + (lane >> 4) * 8;
    int bn = (wn * 32 + (lane & 15)) * 40 + (lane >> 4) * 8;

    for (int ks = 0; ks < 8; ++ks) {
        *(uint4*)la = *(const uint4*)(ga + ks * 32);
        *(uint4*)lb = *(const uint4*)(gb + ks * 32);
        __syncthreads();
        bf16x8 af[2], bfv[2];
        #pragma unroll
        for (int fm = 0; fm < 2; ++fm) af[fm] = *(const bf16x8*)(&Al[am + fm * 16 * 40]);
        #pragma unroll
        for (int fn = 0; fn < 2; ++fn) bfv[fn] = *(const bf16x8*)(&Bl[bn + fn * 16 * 40]);
        #pragma unroll
        for (int fm = 0; fm < 2; ++fm)
            #pragma unroll
            for (int fn = 0; fn < 2; ++fn)
                acc[fm][fn] = __builtin_amdgcn_mfma_f32_16x16x32_bf16(af[fm], bfv[fn], acc[fm][fn], 0, 0, 0);
        __syncthreads();
    }

    int r4 = (lane >> 4) * 4;
    int cn = lane & 15;
    #pragma unroll
    for (int fm = 0; fm < 2; ++fm) {
        int ob = o0 + wm * 32 + fm * 16 + r4;
        #pragma unroll
        for (int fn = 0; fn < 2; ++fn) {
            int n = n0 + wn * 32 + fn * 16 + cn;
            if (ob < 128) {
                ushort4 v;
                v.x = f2bf(acc[fm][fn][0] + bth[ob + 0]);
                v.y = f2bf(acc[fm][fn][1] + bth[ob + 1]);
                v.z = f2bf(acc[fm][fn][2] + bth[ob + 2]);
                v.w = f2bf(acc[fm][fn][3] + bth[ob + 3]);
                *(ushort4*)(&thT[((size_t)(b * N_) + n) * 128 + ob]) = v;
            } else {
                int og = ob - 128;
                #pragma unroll
                for (int r = 0; r < 4; ++r)
                    gT[((size_t)(b * 128) + og + r) * N_ + n] = f2bf(acc[fm][fn][r] + bg[og + r]);
            }
        }
    }
}

// ---------------- K3a: f[q][n] = phi[q]·thetaT[n], K=128 -----------------------
// grid 8*4*49 = 1568, block 256
__global__ __launch_bounds__(256) void k3a_mfma(
    const ushort* __restrict__ phi_bf, const ushort* __restrict__ thT,
    ushort* __restrict__ f)
{
    __shared__ ushort Al[64 * 40];
    __shared__ ushort Bl[64 * 40];
    int bx = blockIdx.x;
    int b = bx & 7; int rest = bx >> 3;
    int mt = rest & 3, nt = rest >> 2;
    int q0 = mt * 64, n0 = nt * 64;
    int t = threadIdx.x;
    int lane = t & 63, w = t >> 6;
    int wm = w >> 1, wn = w & 1;
    int row = t >> 2, chunk = t & 3;

    const ushort* ga = phi_bf + ((size_t)((b << 8) + q0 + row)) * 128 + chunk * 8;
    const ushort* gb = thT + ((size_t)(b * N_) + n0 + row) * 128 + chunk * 8;
    ushort* la = &Al[row * 40 + chunk * 8];
    ushort* lb = &Bl[row * 40 + chunk * 8];

    f32x4 acc[2][2];
    #pragma unroll
    for (int a = 0; a < 2; ++a)
        #pragma unroll
        for (int bb = 0; bb < 2; ++bb) acc[a][bb] = (f32x4){0.f, 0.f, 0.f, 0.f};

    int am = (wm * 32 + (lane & 15)) * 40 + (lane >> 4) * 8;
    int bn = (wn * 32 + (lane & 15)) * 40 + (lane >> 4) * 8;

    #pragma unroll
    for (int ks = 0; ks < 4; ++ks) {
        *(uint4*)la = *(const uint4*)(ga + ks * 32);
        *(uint4*)lb = *(const uint4*)(gb + ks * 32);
        __syncthreads();
        bf16x8 af[2], bfv[2];
        #pragma unroll
        for (int fm = 0; fm < 2; ++fm) af[fm] = *(const bf16x8*)(&Al[am + fm * 16 * 40]);
        #pragma unroll
        for (int fn = 0; fn < 2; ++fn) bfv[fn] = *(const bf16x8*)(&Bl[bn + fn * 16 * 40]);
        #pragma unroll
        for (int fm = 0; fm < 2; ++fm)
            #pragma unroll
            for (int fn = 0; fn < 2; ++fn)
                acc[fm][fn] = __builtin_amdgcn_mfma_f32_16x16x32_bf16(af[fm], bfv[fn], acc[fm][fn], 0, 0, 0);
        __syncthreads();
    }

    int r4 = (lane >> 4) * 4;
    int cn = lane & 15;
    #pragma unroll
    for (int fm = 0; fm < 2; ++fm) {
        int qb = q0 + wm * 32 + fm * 16 + r4;
        #pragma unroll
        for (int fn = 0; fn < 2; ++fn) {
            int n = n0 + wn * 32 + fn * 16 + cn;
            #pragma unroll
            for (int r = 0; r < 4; ++r)
                f[((size_t)((b << 8) + qb + r)) * N_ + n] = f2bf(acc[fm][fn][r]);
        }
    }
}

// ---------------- K3b: in-place row softmax (bf16), 1 block per valid row ------
// grid 8*196 = 1568, block 256
__global__ __launch_bounds__(256) void k3b_softmax(ushort* __restrict__ f)
{
    __shared__ float red[8];
    int bx = blockIdx.x;
    int b = bx / 196, q = bx % 196;
    ushort* rowp = f + ((size_t)((b << 8) + q)) * N_;
    int t = threadIdx.x;
    int lane = t & 63, w = t >> 6;
    bool has2 = (t + 256) < 392;

    uint4 c0 = *(const uint4*)(rowp + t * 8);
    uint4 c1 = has2 ? *(const uint4*)(rowp + (t + 256) * 8) : make_uint4(0, 0, 0, 0);
    float v0[8], v1[8];
    uint u[4] = {c0.x, c0.y, c0.z, c0.w};
    #pragma unroll
    for (int j = 0; j < 4; ++j) {
        v0[2 * j] = __uint_as_float(u[j] << 16);
        v0[2 * j + 1] = __uint_as_float(u[j] & 0xffff0000u);
    }
    uint u1[4] = {c1.x, c1.y, c1.z, c1.w};
    #pragma unroll
    for (int j = 0; j < 4; ++j) {
        v1[2 * j] = __uint_as_float(u1[j] << 16);
        v1[2 * j + 1] = __uint_as_float(u1[j] & 0xffff0000u);
    }

    float m = -1e30f;
    #pragma unroll
    for (int j = 0; j < 8; ++j) m = fmaxf(m, v0[j]);
    if (has2) {
        #pragma unroll
        for (int j = 0; j < 8; ++j) m = fmaxf(m, v1[j]);
    }
    #pragma unroll
    for (int off = 32; off >= 1; off >>= 1) m = fmaxf(m, __shfl_xor(m, off));
    if (lane == 0) red[w] = m;
    __syncthreads();
    m = fmaxf(fmaxf(red[0], red[1]), fmaxf(red[2], red[3]));

    float s = 0.f;
    #pragma unroll
    for (int j = 0; j < 8; ++j) { v0[j] = __expf(v0[j] - m); s += v0[j]; }
    if (has2) {
        #pragma unroll
        for (int j = 0; j < 8; ++j) { v1[j] = __expf(v1[j] - m); s += v1[j]; }
    }
    #pragma unroll
    for (int off = 32; off >= 1; off >>= 1) s += __shfl_xor(s, off);
    if (lane == 0) red[4 + w] = s;
    __syncthreads();
    float inv = 1.0f / (((red[4] + red[5]) + (red[6] + red[7])));

    uint4 o0, o1;
    o0.x = pack2(v0[0] * inv, v0[1] * inv);
    o0.y = pack2(v0[2] * inv, v0[3] * inv);
    o0.z = pack2(v0[4] * inv, v0[5] * inv);
    o0.w = pack2(v0[6] * inv, v0[7] * inv);
    *(uint4*)(rowp + t * 8) = o0;
    if (has2) {
        o1.x = pack2(v1[0] * inv, v1[1] * inv);
        o1.y = pack2(v1[2] * inv, v1[3] * inv);
        o1.z = pack2(v1[4] * inv, v1[5] * inv);
        o1.w = pack2(v1[6] * inv, v1[7] * inv);
        *(uint4*)(rowp + (t + 256) * 8) = o1;
    }
}

// ---------------- K3c: y[q][i] = sum_n p[q][n]·gT[i][n], K=3136, K-split 7 ------
// grid 8*4*2*7 = 448, block 256; atomicAdd into zeroed y
__global__ __launch_bounds__(256) void k3c_mfma(
    const ushort* __restrict__ p, const ushort* __restrict__ gT,
    float* __restrict__ y_ws)
{
    __shared__ ushort Al[64 * 40];
    __shared__ ushort Bl[64 * 40];
    int bx = blockIdx.x;
    int b = bx & 7; int rest = bx >> 3;          // 0..55
    int mt = rest & 3; int rest2 = rest >> 2;    // 0..13
    int it = rest2 & 1, ksp = rest2 >> 1;        // it 0..1, ksp 0..6
    int q0 = mt * 64, i0 = it * 64, kbase = ksp * 448;
    int t = threadIdx.x;
    int lane = t & 63, w = t >> 6;
    int wm = w >> 1, wn = w & 1;
    int row = t >> 2, chunk = t & 3;

    const ushort* ga = p + ((size_t)((b << 8) + q0 + row)) * N_ + kbase + chunk * 8;
    const ushort* gb = gT + ((size_t)(b * 128) + i0 + row) * N_ + kbase + chunk * 8;
    ushort* la = &Al[row * 40 + chunk * 8];
    ushort* lb = &Bl[row * 40 + chunk * 8];

    f32x4 acc[2][2];
    #pragma unroll
    for (int a = 0; a < 2; ++a)
        #pragma unroll
        for (int bb = 0; bb < 2; ++bb) acc[a][bb] = (f32x4){0.f, 0.f, 0.f, 0.f};

    int am = (wm * 32 + (lane & 15)) * 40 + (lane >> 4) * 8;
    int bn = (wn * 32 + (lane & 15)) * 40 + (lane >> 4) * 8;

    for (int ks = 0; ks < 14; ++ks) {
        *(uint4*)la = *(const uint4*)(ga + ks * 32);
        *(uint4*)lb = *(const uint4*)(gb + ks * 32);
        __syncthreads();
        bf16x8 af[2], bfv[2];
        #pragma unroll
        for (int fm = 0; fm < 2; ++fm) af[fm] = *(const bf16x8*)(&Al[am + fm * 16 * 40]);
        #pragma unroll
        for (int fn = 0; fn < 2; ++fn) bfv[fn] = *(const bf16x8*)(&Bl[bn + fn * 16 * 40]);
        #pragma unroll
        for (int fm = 0; fm < 2; ++fm)
            #pragma unroll
            for (int fn = 0; fn < 2; ++fn)
                acc[fm][fn] = __builtin_amdgcn_mfma_f32_16x16x32_bf16(af[fm], bfv[fn], acc[fm][fn], 0, 0, 0);
        __syncthreads();
    }

    int r4 = (lane >> 4) * 4;
    int cn = lane & 15;
    #pragma unroll
    for (int fm = 0; fm < 2; ++fm) {
        int qb = q0 + wm * 32 + fm * 16 + r4;
        #pragma unroll
        for (int fn = 0; fn < 2; ++fn) {
            int i = i0 + wn * 32 + fn * 16 + cn;
            #pragma unroll
            for (int r = 0; r < 4; ++r) {
                int q = qb + r;
                if (q < NQ_)
                    atomicAdd(&y_ws[((size_t)(b * NQ_) + q) * 128 + i], acc[fm][fn][r]);
            }
        }
    }
}

// ---------------- K4a: z = BN2(Wz @ y + bz) on 196-grid -------------------------
// grid: B*25, block 256
__global__ __launch_bounds__(256) void k4a_z(
    const float* __restrict__ y_ws, const float* __restrict__ Wz, const float* __restrict__ bz,
    const float* __restrict__ g2, const float* __restrict__ b2,
    const float* __restrict__ rm2, const float* __restrict__ rv2,
    float* __restrict__ z_ws)
{
    __shared__ float ys[8][128];
    int bx = blockIdx.x;
    int b = bx / 25, qt = bx % 25;
    int q0 = qt * 8;
    int t = threadIdx.x;
    #pragma unroll
    for (int rr = 0; rr < 4; ++rr) {
        int idx = t + rr * 256;
        int p = idx >> 7, ii = idx & 127;
        int q = q0 + p;
        ys[p][ii] = (q < NQ_) ? y_ws[(size_t)b * NQ_ * CI_ + (size_t)q * CI_ + ii] : 0.0f;
    }
    __syncthreads();
    int c = t;
    float acc[8] = {0, 0, 0, 0, 0, 0, 0, 0};
    const float* wrow = Wz + (size_t)c * 128;
    for (int i4 = 0; i4 < 32; ++i4) {
        float4 w = *(const float4*)(wrow + i4 * 4);
        #pragma unroll
        for (int p = 0; p < 8; ++p) {
            float4 yv = *(const float4*)(&ys[p][i4 * 4]);
            acc[p] += w.x * yv.x + w.y * yv.y + w.z * yv.z + w.w * yv.w;
        }
    }
    float inv2 = g2[c] * rsqrtf(rv2[c] + 1e-5f);
    float add2 = b2[c] - rm2[c] * inv2;
    float bzc = bz[c];
    #pragma unroll
    for (int p = 0; p < 8; ++p) {
        int q = q0 + p;
        if (q < NQ_)
            z_ws[(size_t)b * C_ * NQ_ + (size_t)c * NQ_ + q] = (acc[p] + bzc) * inv2 + add2;
    }
}

// ---------------- K4b: out = upsample(z) + x_cnn --------------------------------
// grid 6272, block 256, one float4 per thread
__global__ __launch_bounds__(256) void k4b_out(
    const float* __restrict__ x_cnn, const float* __restrict__ z_ws, float* __restrict__ out)
{
    int idx = blockIdx.x * 256 + threadIdx.x;   // float4 index over (B,C,56,14)
    int w4 = idx % 14;
    int rest = idx / 14;
    int h = rest % 56;
    rest /= 56;
    int c = rest % 256;
    int b = rest / 256;
    int q = (h >> 2) * 14 + w4;
    float z = z_ws[((size_t)b * C_ + c) * NQ_ + q];
    float4 xv = *(const float4*)(x_cnn + (size_t)idx * 4);
    float4 o = make_float4(xv.x + z, xv.y + z, xv.z + z, xv.w + z);
    *(float4*)(out + (size_t)idx * 4) = o;
}

extern "C" void kernel_launch(void* const* d_in, const int* in_sizes, int n_in,
                              void* d_out, int out_size, void* d_ws, size_t ws_size,
                              hipStream_t stream) {
    const float* x_t   = (const float*)d_in[0];
    const float* x_cnn = (const float*)d_in[1];
    const float* Wp  = (const float*)d_in[2];
    const float* bp  = (const float*)d_in[3];
    const float* g1  = (const float*)d_in[4];
    const float* b1  = (const float*)d_in[5];
    const float* rm1 = (const float*)d_in[6];
    const float* rv1 = (const float*)d_in[7];
    const float* Wg  = (const float*)d_in[8];
    const float* bg  = (const float*)d_in[9];
    const float* Wth = (const float*)d_in[10];
    const float* bth = (const float*)d_in[11];
    const float* Wph = (const float*)d_in[12];
    const float* bph = (const float*)d_in[13];
    const float* Wz  = (const float*)d_in[14];
    const float* bz  = (const float*)d_in[15];
    const float* g2  = (const float*)d_in[16];
    const float* b2  = (const float*)d_in[17];
    const float* rm2 = (const float*)d_in[18];
    const float* rv2 = (const float*)d_in[19];
    float* out = (float*)d_out;

    char* ws = (char*)d_ws;
    // region 0: xT bf16 [8][3136][256] then (after k2) f/p bf16 [8][256][3136] — both 12,845,056 B
    ushort* xT   = (ushort*)(ws);
    ushort* f_ws = (ushort*)(ws);
    ushort* thT  = (ushort*)(ws + 12845056);      // bf16 [8][3136][128] = 6,422,528
    ushort* gT   = (ushort*)(ws + 19267584);      // bf16 [8][128][3136] = 6,422,528
    ushort* phi  = (ushort*)(ws + 25690112);      // bf16 [8][256][128]  = 524,288
    float*  y_ws = (float*)(ws + 26214400);       // fp32 [8][196][128]  = 802,816
    float*  z_ws = (float*)(ws + 27017216);       // fp32 [8][256][196]  = 1,605,632
    ushort* Wcomb= (ushort*)(ws + 28622848);      // bf16 [256][256]     = 131,072

    kconv_w<<<dim3(256), dim3(256), 0, stream>>>(Wth, Wg, Wcomb, y_ws);
    k0_xT<<<dim3(1568), dim3(256), 0, stream>>>(x_cnn, xT);
    k1_fcuup_phi<<<dim3(256), dim3(256), 0, stream>>>(x_t, Wp, bp, g1, b1, rm1, rv1, Wph, bph, phi);
    k2_mfma<<<dim3(1568), dim3(256), 0, stream>>>(Wcomb, bth, bg, xT, thT, gT);
    k3a_mfma<<<dim3(1568), dim3(256), 0, stream>>>(phi, thT, f_ws);
    k3b_softmax<<<dim3(1568), dim3(256), 0, stream>>>(f_ws);
    k3c_mfma<<<dim3(448), dim3(256), 0, stream>>>(f_ws, gT, y_ws);
    k4a_z<<<dim3(200), dim3(256), 0, stream>>>(y_ws, Wz, bz, g2, b2, rm2, rv2, z_ws);
    k4b_out<<<dim3(6272), dim3(256), 0, stream>>>(x_cnn, z_ws, out);
}

// Round 3
// 103.207 us; speedup vs baseline: 2.5513x; 1.3856x over previous
//
#include <hip/hip_runtime.h>
#include <hip/hip_bf16.h>

// Shapes (fixed): B=8, E=768, C=256, CI=128, H=W=14, UP=4 -> H2=W2=56, N=3136, NQ=196
#define B_ 8
#define E_ 768
#define C_ 256
#define CI_ 128
#define NQ_ 196
#define N_ 3136

typedef short bf16x8 __attribute__((ext_vector_type(8)));
typedef float f32x4 __attribute__((ext_vector_type(4)));

__device__ __forceinline__ ushort f2bf(float x) {
    union { float f; uint u; } v; v.f = x;
    uint r = v.u + 0x7FFFu + ((v.u >> 16) & 1u);   // RNE
    return (ushort)(r >> 16);
}
__device__ __forceinline__ uint pack2(float a, float b) {
    return (uint)f2bf(a) | ((uint)f2bf(b) << 16);
}

// ---------------- kconv: weights -> bf16 (BN1 folded into Wp), zero y ----------
// grid 256, block 256
__global__ __launch_bounds__(256) void kconv_w(
    const float* __restrict__ Wth, const float* __restrict__ Wg,
    const float* __restrict__ Wp, const float* __restrict__ g1, const float* __restrict__ rv1,
    const float* __restrict__ Wph,
    ushort* __restrict__ Wcomb, ushort* __restrict__ Wp_bf, ushort* __restrict__ Wph_bf,
    float* __restrict__ y_ws)
{
    int idx = blockIdx.x * 256 + threadIdx.x;     // 0..65535
    int o = idx >> 8, c = idx & 255;
    float v = (o < 128) ? Wth[o * 256 + c] : Wg[(o - 128) * 256 + c];
    Wcomb[idx] = f2bf(v);
    // Wp scaled by inv1 (BN fold): 256*768 = 196608
    for (int i = idx; i < 196608; i += 65536) {
        int oo = i / 768;
        float inv1 = g1[oo] * rsqrtf(rv1[oo] + 1e-6f);
        Wp_bf[i] = f2bf(Wp[i] * inv1);
    }
    if (idx < 32768) Wph_bf[idx] = f2bf(Wph[idx]);
    for (int i = idx; i < B_ * NQ_ * CI_; i += 65536) y_ws[i] = 0.0f;
}

// ---------------- k0: x_cnn [b][c][n] fp32 -> xT [b][n][c] bf16 ----------------
// grid 8*4*49 = 1568, block 256
__global__ __launch_bounds__(256) void k0_xT(
    const float* __restrict__ x_cnn, ushort* __restrict__ xT)
{
    __shared__ float Xs[64][68];
    int bx = blockIdx.x;
    int b = bx & 7; int rest = bx >> 3;
    int ct = rest & 3, nt = rest >> 2;            // ct 0..3, nt 0..48
    int c0 = ct * 64, n0 = nt * 64;
    int t = threadIdx.x;
    #pragma unroll
    for (int rr = 0; rr < 4; ++rr) {
        int idx = t + rr * 256;                   // 0..1023
        int c = idx >> 4, n4 = idx & 15;
        float4 v = *(const float4*)(x_cnn + ((size_t)(b * C_) + c0 + c) * N_ + n0 + n4 * 4);
        *(float4*)(&Xs[c][n4 * 4]) = v;
    }
    __syncthreads();
    int n = t & 63, cc = t >> 6;                  // cc 0..3 (16 c each)
    ushort vals[16];
    #pragma unroll
    for (int j = 0; j < 16; ++j)
        vals[j] = f2bf(Xs[cc * 16 + j][n]);
    ushort* outp = xT + ((size_t)(b * N_) + n0 + n) * 256 + c0 + cc * 16;
    *(uint4*)(outp) = *(const uint4*)(&vals[0]);
    *(uint4*)(outp + 8) = *(const uint4*)(&vals[8]);
}

// ---------------- K1a: xact = relu(BN(x_t @ Wp^T)) via MFMA --------------------
// grid 8*4*4 = 128, block 256 (4 waves, 64x64 tile), K=768
__global__ __launch_bounds__(256) void k1a_proj(
    const float* __restrict__ x_t, const ushort* __restrict__ Wp_bf,
    const float* __restrict__ bp, const float* __restrict__ g1, const float* __restrict__ b1,
    const float* __restrict__ rm1, const float* __restrict__ rv1,
    ushort* __restrict__ xact)
{
    __shared__ ushort Al[64 * 40];
    __shared__ ushort Bl[64 * 40];
    int bx = blockIdx.x;
    int b = bx & 7; int rest = bx >> 3;
    int mt = rest & 3, nt = rest >> 2;
    int q0 = mt * 64, c0 = nt * 64;
    int t = threadIdx.x;
    int lane = t & 63, w = t >> 6;
    int wm = w >> 1, wn = w & 1;
    int row = t >> 2, chunk = t & 3;

    bool arow_ok = (q0 + row) < NQ_;
    const float* gax = x_t + (size_t)b * 197 * 768 + (size_t)(1 + q0 + row) * 768 + chunk * 8;
    const ushort* gb = Wp_bf + (size_t)(c0 + row) * 768 + chunk * 8;
    ushort* la = &Al[row * 40 + chunk * 8];
    ushort* lb = &Bl[row * 40 + chunk * 8];

    f32x4 acc[2][2];
    #pragma unroll
    for (int a = 0; a < 2; ++a)
        #pragma unroll
        for (int bb = 0; bb < 2; ++bb) acc[a][bb] = (f32x4){0.f, 0.f, 0.f, 0.f};

    int am = (wm * 32 + (lane & 15)) * 40 + (lane >> 4) * 8;
    int bn = (wn * 32 + (lane & 15)) * 40 + (lane >> 4) * 8;

    for (int ks = 0; ks < 24; ++ks) {
        uint4 aw = make_uint4(0, 0, 0, 0);
        if (arow_ok) {
            float4 x0 = *(const float4*)(gax + ks * 32);
            float4 x1 = *(const float4*)(gax + ks * 32 + 4);
            aw.x = pack2(x0.x, x0.y); aw.y = pack2(x0.z, x0.w);
            aw.z = pack2(x1.x, x1.y); aw.w = pack2(x1.z, x1.w);
        }
        uint4 bw = *(const uint4*)(gb + ks * 32);
        __syncthreads();
        *(uint4*)la = aw;
        *(uint4*)lb = bw;
        __syncthreads();
        bf16x8 af[2], bfv[2];
        #pragma unroll
        for (int fm = 0; fm < 2; ++fm) af[fm] = *(const bf16x8*)(&Al[am + fm * 16 * 40]);
        #pragma unroll
        for (int fn = 0; fn < 2; ++fn) bfv[fn] = *(const bf16x8*)(&Bl[bn + fn * 16 * 40]);
        #pragma unroll
        for (int fm = 0; fm < 2; ++fm)
            #pragma unroll
            for (int fn = 0; fn < 2; ++fn)
                acc[fm][fn] = __builtin_amdgcn_mfma_f32_16x16x32_bf16(af[fm], bfv[fn], acc[fm][fn], 0, 0, 0);
    }

    int r4 = (lane >> 4) * 4;
    int cn = lane & 15;
    #pragma unroll
    for (int fn = 0; fn < 2; ++fn) {
        int c = c0 + wn * 32 + fn * 16 + cn;
        float inv1 = g1[c] * rsqrtf(rv1[c] + 1e-6f);
        float badd = bp[c] * inv1 + b1[c] - rm1[c] * inv1;
        #pragma unroll
        for (int fm = 0; fm < 2; ++fm) {
            int q = q0 + wm * 32 + fm * 16 + r4;
            #pragma unroll
            for (int r = 0; r < 4; ++r) {
                float vv = fmaxf(acc[fm][fn][r] + badd, 0.0f);
                xact[((size_t)((b << 8) + q + r)) * 256 + c] = f2bf(vv);
            }
        }
    }
}

// ---------------- K1b: phi = xact @ Wph^T + bph via MFMA -----------------------
// grid 8*4*2 = 64, block 256, K=256
__global__ __launch_bounds__(256) void k1b_phi(
    const ushort* __restrict__ xact, const ushort* __restrict__ Wph_bf,
    const float* __restrict__ bph, ushort* __restrict__ phi_bf)
{
    __shared__ ushort Al[64 * 40];
    __shared__ ushort Bl[64 * 40];
    int bx = blockIdx.x;
    int b = bx & 7; int rest = bx >> 3;
    int mt = rest & 3, nt = rest >> 2;           // nt 0..1
    int q0 = mt * 64, i0 = nt * 64;
    int t = threadIdx.x;
    int lane = t & 63, w = t >> 6;
    int wm = w >> 1, wn = w & 1;
    int row = t >> 2, chunk = t & 3;

    const ushort* ga = xact + ((size_t)((b << 8) + q0 + row)) * 256 + chunk * 8;
    const ushort* gb = Wph_bf + (size_t)(i0 + row) * 256 + chunk * 8;
    ushort* la = &Al[row * 40 + chunk * 8];
    ushort* lb = &Bl[row * 40 + chunk * 8];

    f32x4 acc[2][2];
    #pragma unroll
    for (int a = 0; a < 2; ++a)
        #pragma unroll
        for (int bb = 0; bb < 2; ++bb) acc[a][bb] = (f32x4){0.f, 0.f, 0.f, 0.f};

    int am = (wm * 32 + (lane & 15)) * 40 + (lane >> 4) * 8;
    int bn = (wn * 32 + (lane & 15)) * 40 + (lane >> 4) * 8;

    #pragma unroll
    for (int ks = 0; ks < 8; ++ks) {
        uint4 aw = *(const uint4*)(ga + ks * 32);
        uint4 bw = *(const uint4*)(gb + ks * 32);
        __syncthreads();
        *(uint4*)la = aw;
        *(uint4*)lb = bw;
        __syncthreads();
        bf16x8 af[2], bfv[2];
        #pragma unroll
        for (int fm = 0; fm < 2; ++fm) af[fm] = *(const bf16x8*)(&Al[am + fm * 16 * 40]);
        #pragma unroll
        for (int fn = 0; fn < 2; ++fn) bfv[fn] = *(const bf16x8*)(&Bl[bn + fn * 16 * 40]);
        #pragma unroll
        for (int fm = 0; fm < 2; ++fm)
            #pragma unroll
            for (int fn = 0; fn < 2; ++fn)
                acc[fm][fn] = __builtin_amdgcn_mfma_f32_16x16x32_bf16(af[fm], bfv[fn], acc[fm][fn], 0, 0, 0);
    }

    int r4 = (lane >> 4) * 4;
    int cn = lane & 15;
    #pragma unroll
    for (int fn = 0; fn < 2; ++fn) {
        int i = i0 + wn * 32 + fn * 16 + cn;
        float bias = bph[i];
        #pragma unroll
        for (int fm = 0; fm < 2; ++fm) {
            int q = q0 + wm * 32 + fm * 16 + r4;
            #pragma unroll
            for (int r = 0; r < 4; ++r) {
                ushort val = ((q + r) < NQ_) ? f2bf(acc[fm][fn][r] + bias) : (ushort)0;
                phi_bf[((size_t)((b << 8) + q + r)) * 128 + i] = val;
            }
        }
    }
}

// ---------------- K2: MFMA GEMM out[o][n] = Wcomb[o]·xT[n], K=256 --------------
// grid 8*4*49 = 1568 (b = bx&7), block 256 (4 waves, 64x64 tile)
__global__ __launch_bounds__(256) void k2_mfma(
    const ushort* __restrict__ Wcomb, const float* __restrict__ bth, const float* __restrict__ bg,
    const ushort* __restrict__ xT, ushort* __restrict__ thT, ushort* __restrict__ gT)
{
    __shared__ ushort Al[64 * 40];   // rows padded to 80B
    __shared__ ushort Bl[64 * 40];
    int bx = blockIdx.x;
    int b = bx & 7; int rest = bx >> 3;
    int mt = rest & 3, nt = rest >> 2;
    int o0 = mt * 64, n0 = nt * 64;
    int t = threadIdx.x;
    int lane = t & 63, w = t >> 6;
    int wm = w >> 1, wn = w & 1;
    int row = t >> 2, chunk = t & 3;

    const ushort* ga = Wcomb + (size_t)(o0 + row) * 256 + chunk * 8;
    const ushort* gb = xT + ((size_t)(b * N_) + n0 + row) * 256 + chunk * 8;
    ushort* la = &Al[row * 40 + chunk * 8];
    ushort* lb = &Bl[row * 40 + chunk * 8];

    f32x4 acc[2][2];
    #pragma unroll
    for (int a = 0; a < 2; ++a)
        #pragma unroll
        for (int bb = 0; bb < 2; ++bb) acc[a][bb] = (f32x4){0.f, 0.f, 0.f, 0.f};

    int am = (wm * 32 + (lane & 15)) * 40 + (lane >> 4) * 8;
    int bn = (wn * 32 + (lane & 15)) * 40 + (lane >> 4) * 8;

    for (int ks = 0; ks < 8; ++ks) {
        uint4 aw = *(const uint4*)(ga + ks * 32);
        uint4 bw = *(const uint4*)(gb + ks * 32);
        __syncthreads();
        *(uint4*)la = aw;
        *(uint4*)lb = bw;
        __syncthreads();
        bf16x8 af[2], bfv[2];
        #pragma unroll
        for (int fm = 0; fm < 2; ++fm) af[fm] = *(const bf16x8*)(&Al[am + fm * 16 * 40]);
        #pragma unroll
        for (int fn = 0; fn < 2; ++fn) bfv[fn] = *(const bf16x8*)(&Bl[bn + fn * 16 * 40]);
        #pragma unroll
        for (int fm = 0; fm < 2; ++fm)
            #pragma unroll
            for (int fn = 0; fn < 2; ++fn)
                acc[fm][fn] = __builtin_amdgcn_mfma_f32_16x16x32_bf16(af[fm], bfv[fn], acc[fm][fn], 0, 0, 0);
    }

    int r4 = (lane >> 4) * 4;
    int cn = lane & 15;
    #pragma unroll
    for (int fm = 0; fm < 2; ++fm) {
        int ob = o0 + wm * 32 + fm * 16 + r4;
        #pragma unroll
        for (int fn = 0; fn < 2; ++fn) {
            int n = n0 + wn * 32 + fn * 16 + cn;
            if (ob < 128) {
                ushort4 v;
                v.x = f2bf(acc[fm][fn][0] + bth[ob + 0]);
                v.y = f2bf(acc[fm][fn][1] + bth[ob + 1]);
                v.z = f2bf(acc[fm][fn][2] + bth[ob + 2]);
                v.w = f2bf(acc[fm][fn][3] + bth[ob + 3]);
                *(ushort4*)(&thT[((size_t)(b * N_) + n) * 128 + ob]) = v;
            } else {
                int og = ob - 128;
                #pragma unroll
                for (int r = 0; r < 4; ++r)
                    gT[((size_t)(b * 128) + og + r) * N_ + n] = f2bf(acc[fm][fn][r] + bg[og + r]);
            }
        }
    }
}

// ---------------- K3a: f[q][n] = phi[q]·thetaT[n], K=128 -----------------------
// grid 8*4*49 = 1568, block 256
__global__ __launch_bounds__(256) void k3a_mfma(
    const ushort* __restrict__ phi_bf, const ushort* __restrict__ thT,
    ushort* __restrict__ f)
{
    __shared__ ushort Al[64 * 40];
    __shared__ ushort Bl[64 * 40];
    int bx = blockIdx.x;
    int b = bx & 7; int rest = bx >> 3;
    int mt = rest & 3, nt = rest >> 2;
    int q0 = mt * 64, n0 = nt * 64;
    int t = threadIdx.x;
    int lane = t & 63, w = t >> 6;
    int wm = w >> 1, wn = w & 1;
    int row = t >> 2, chunk = t & 3;

    const ushort* ga = phi_bf + ((size_t)((b << 8) + q0 + row)) * 128 + chunk * 8;
    const ushort* gb = thT + ((size_t)(b * N_) + n0 + row) * 128 + chunk * 8;
    ushort* la = &Al[row * 40 + chunk * 8];
    ushort* lb = &Bl[row * 40 + chunk * 8];

    f32x4 acc[2][2];
    #pragma unroll
    for (int a = 0; a < 2; ++a)
        #pragma unroll
        for (int bb = 0; bb < 2; ++bb) acc[a][bb] = (f32x4){0.f, 0.f, 0.f, 0.f};

    int am = (wm * 32 + (lane & 15)) * 40 + (lane >> 4) * 8;
    int bn = (wn * 32 + (lane & 15)) * 40 + (lane >> 4) * 8;

    #pragma unroll
    for (int ks = 0; ks < 4; ++ks) {
        uint4 aw = *(const uint4*)(ga + ks * 32);
        uint4 bw = *(const uint4*)(gb + ks * 32);
        __syncthreads();
        *(uint4*)la = aw;
        *(uint4*)lb = bw;
        __syncthreads();
        bf16x8 af[2], bfv[2];
        #pragma unroll
        for (int fm = 0; fm < 2; ++fm) af[fm] = *(const bf16x8*)(&Al[am + fm * 16 * 40]);
        #pragma unroll
        for (int fn = 0; fn < 2; ++fn) bfv[fn] = *(const bf16x8*)(&Bl[bn + fn * 16 * 40]);
        #pragma unroll
        for (int fm = 0; fm < 2; ++fm)
            #pragma unroll
            for (int fn = 0; fn < 2; ++fn)
                acc[fm][fn] = __builtin_amdgcn_mfma_f32_16x16x32_bf16(af[fm], bfv[fn], acc[fm][fn], 0, 0, 0);
    }

    int r4 = (lane >> 4) * 4;
    int cn = lane & 15;
    #pragma unroll
    for (int fm = 0; fm < 2; ++fm) {
        int qb = q0 + wm * 32 + fm * 16 + r4;
        #pragma unroll
        for (int fn = 0; fn < 2; ++fn) {
            int n = n0 + wn * 32 + fn * 16 + cn;
            #pragma unroll
            for (int r = 0; r < 4; ++r)
                f[((size_t)((b << 8) + qb + r)) * N_ + n] = f2bf(acc[fm][fn][r]);
        }
    }
}

// ---------------- K3b: in-place row softmax (bf16), 1 block per valid row ------
// grid 8*196 = 1568, block 256
__global__ __launch_bounds__(256) void k3b_softmax(ushort* __restrict__ f)
{
    __shared__ float red[8];
    int bx = blockIdx.x;
    int b = bx / 196, q = bx % 196;
    ushort* rowp = f + ((size_t)((b << 8) + q)) * N_;
    int t = threadIdx.x;
    int lane = t & 63, w = t >> 6;
    bool has2 = (t + 256) < 392;

    uint4 c0 = *(const uint4*)(rowp + t * 8);
    uint4 c1 = has2 ? *(const uint4*)(rowp + (t + 256) * 8) : make_uint4(0, 0, 0, 0);
    float v0[8], v1[8];
    uint u[4] = {c0.x, c0.y, c0.z, c0.w};
    #pragma unroll
    for (int j = 0; j < 4; ++j) {
        v0[2 * j] = __uint_as_float(u[j] << 16);
        v0[2 * j + 1] = __uint_as_float(u[j] & 0xffff0000u);
    }
    uint u1[4] = {c1.x, c1.y, c1.z, c1.w};
    #pragma unroll
    for (int j = 0; j < 4; ++j) {
        v1[2 * j] = __uint_as_float(u1[j] << 16);
        v1[2 * j + 1] = __uint_as_float(u1[j] & 0xffff0000u);
    }

    float m = -1e30f;
    #pragma unroll
    for (int j = 0; j < 8; ++j) m = fmaxf(m, v0[j]);
    if (has2) {
        #pragma unroll
        for (int j = 0; j < 8; ++j) m = fmaxf(m, v1[j]);
    }
    #pragma unroll
    for (int off = 32; off >= 1; off >>= 1) m = fmaxf(m, __shfl_xor(m, off));
    if (lane == 0) red[w] = m;
    __syncthreads();
    m = fmaxf(fmaxf(red[0], red[1]), fmaxf(red[2], red[3]));

    float s = 0.f;
    #pragma unroll
    for (int j = 0; j < 8; ++j) { v0[j] = __expf(v0[j] - m); s += v0[j]; }
    if (has2) {
        #pragma unroll
        for (int j = 0; j < 8; ++j) { v1[j] = __expf(v1[j] - m); s += v1[j]; }
    }
    #pragma unroll
    for (int off = 32; off >= 1; off >>= 1) s += __shfl_xor(s, off);
    if (lane == 0) red[4 + w] = s;
    __syncthreads();
    float inv = 1.0f / (((red[4] + red[5]) + (red[6] + red[7])));

    uint4 o0, o1;
    o0.x = pack2(v0[0] * inv, v0[1] * inv);
    o0.y = pack2(v0[2] * inv, v0[3] * inv);
    o0.z = pack2(v0[4] * inv, v0[5] * inv);
    o0.w = pack2(v0[6] * inv, v0[7] * inv);
    *(uint4*)(rowp + t * 8) = o0;
    if (has2) {
        o1.x = pack2(v1[0] * inv, v1[1] * inv);
        o1.y = pack2(v1[2] * inv, v1[3] * inv);
        o1.z = pack2(v1[4] * inv, v1[5] * inv);
        o1.w = pack2(v1[6] * inv, v1[7] * inv);
        *(uint4*)(rowp + (t + 256) * 8) = o1;
    }
}

// ---------------- K3c: y[q][i] = sum_n p[q][n]·gT[i][n], K=3136, K-split 7 ------
// grid 8*4*2*7 = 448, block 256; atomicAdd into zeroed y
__global__ __launch_bounds__(256) void k3c_mfma(
    const ushort* __restrict__ p, const ushort* __restrict__ gT,
    float* __restrict__ y_ws)
{
    __shared__ ushort Al[64 * 40];
    __shared__ ushort Bl[64 * 40];
    int bx = blockIdx.x;
    int b = bx & 7; int rest = bx >> 3;          // 0..55
    int mt = rest & 3; int rest2 = rest >> 2;    // 0..13
    int it = rest2 & 1, ksp = rest2 >> 1;        // it 0..1, ksp 0..6
    int q0 = mt * 64, i0 = it * 64, kbase = ksp * 448;
    int t = threadIdx.x;
    int lane = t & 63, w = t >> 6;
    int wm = w >> 1, wn = w & 1;
    int row = t >> 2, chunk = t & 3;

    const ushort* ga = p + ((size_t)((b << 8) + q0 + row)) * N_ + kbase + chunk * 8;
    const ushort* gb = gT + ((size_t)(b * 128) + i0 + row) * N_ + kbase + chunk * 8;
    ushort* la = &Al[row * 40 + chunk * 8];
    ushort* lb = &Bl[row * 40 + chunk * 8];

    f32x4 acc[2][2];
    #pragma unroll
    for (int a = 0; a < 2; ++a)
        #pragma unroll
        for (int bb = 0; bb < 2; ++bb) acc[a][bb] = (f32x4){0.f, 0.f, 0.f, 0.f};

    int am = (wm * 32 + (lane & 15)) * 40 + (lane >> 4) * 8;
    int bn = (wn * 32 + (lane & 15)) * 40 + (lane >> 4) * 8;

    for (int ks = 0; ks < 14; ++ks) {
        uint4 aw = *(const uint4*)(ga + ks * 32);
        uint4 bw = *(const uint4*)(gb + ks * 32);
        __syncthreads();
        *(uint4*)la = aw;
        *(uint4*)lb = bw;
        __syncthreads();
        bf16x8 af[2], bfv[2];
        #pragma unroll
        for (int fm = 0; fm < 2; ++fm) af[fm] = *(const bf16x8*)(&Al[am + fm * 16 * 40]);
        #pragma unroll
        for (int fn = 0; fn < 2; ++fn) bfv[fn] = *(const bf16x8*)(&Bl[bn + fn * 16 * 40]);
        #pragma unroll
        for (int fm = 0; fm < 2; ++fm)
            #pragma unroll
            for (int fn = 0; fn < 2; ++fn)
                acc[fm][fn] = __builtin_amdgcn_mfma_f32_16x16x32_bf16(af[fm], bfv[fn], acc[fm][fn], 0, 0, 0);
    }

    int r4 = (lane >> 4) * 4;
    int cn = lane & 15;
    #pragma unroll
    for (int fm = 0; fm < 2; ++fm) {
        int qb = q0 + wm * 32 + fm * 16 + r4;
        #pragma unroll
        for (int fn = 0; fn < 2; ++fn) {
            int i = i0 + wn * 32 + fn * 16 + cn;
            #pragma unroll
            for (int r = 0; r < 4; ++r) {
                int q = qb + r;
                if (q < NQ_)
                    atomicAdd(&y_ws[((size_t)(b * NQ_) + q) * 128 + i], acc[fm][fn][r]);
            }
        }
    }
}

// ---------------- K4a: z = BN2(Wz @ y + bz) on 196-grid -------------------------
// grid: B*25, block 256
__global__ __launch_bounds__(256) void k4a_z(
    const float* __restrict__ y_ws, const float* __restrict__ Wz, const float* __restrict__ bz,
    const float* __restrict__ g2, const float* __restrict__ b2,
    const float* __restrict__ rm2, const float* __restrict__ rv2,
    float* __restrict__ z_ws)
{
    __shared__ float ys[8][128];
    int bx = blockIdx.x;
    int b = bx / 25, qt = bx % 25;
    int q0 = qt * 8;
    int t = threadIdx.x;
    #pragma unroll
    for (int rr = 0; rr < 4; ++rr) {
        int idx = t + rr * 256;
        int p = idx >> 7, ii = idx & 127;
        int q = q0 + p;
        ys[p][ii] = (q < NQ_) ? y_ws[(size_t)b * NQ_ * CI_ + (size_t)q * CI_ + ii] : 0.0f;
    }
    __syncthreads();
    int c = t;
    float acc[8] = {0, 0, 0, 0, 0, 0, 0, 0};
    const float* wrow = Wz + (size_t)c * 128;
    for (int i4 = 0; i4 < 32; ++i4) {
        float4 w = *(const float4*)(wrow + i4 * 4);
        #pragma unroll
        for (int p = 0; p < 8; ++p) {
            float4 yv = *(const float4*)(&ys[p][i4 * 4]);
            acc[p] += w.x * yv.x + w.y * yv.y + w.z * yv.z + w.w * yv.w;
        }
    }
    float inv2 = g2[c] * rsqrtf(rv2[c] + 1e-5f);
    float add2 = b2[c] - rm2[c] * inv2;
    float bzc = bz[c];
    #pragma unroll
    for (int p = 0; p < 8; ++p) {
        int q = q0 + p;
        if (q < NQ_)
            z_ws[(size_t)b * C_ * NQ_ + (size_t)c * NQ_ + q] = (acc[p] + bzc) * inv2 + add2;
    }
}

// ---------------- K4b: out = upsample(z) + x_cnn --------------------------------
// grid 6272, block 256, one float4 per thread
__global__ __launch_bounds__(256) void k4b_out(
    const float* __restrict__ x_cnn, const float* __restrict__ z_ws, float* __restrict__ out)
{
    int idx = blockIdx.x * 256 + threadIdx.x;   // float4 index over (B,C,56,14)
    int w4 = idx % 14;
    int rest = idx / 14;
    int h = rest % 56;
    rest /= 56;
    int c = rest % 256;
    int b = rest / 256;
    int q = (h >> 2) * 14 + w4;
    float z = z_ws[((size_t)b * C_ + c) * NQ_ + q];
    float4 xv = *(const float4*)(x_cnn + (size_t)idx * 4);
    float4 o = make_float4(xv.x + z, xv.y + z, xv.z + z, xv.w + z);
    *(float4*)(out + (size_t)idx * 4) = o;
}

extern "C" void kernel_launch(void* const* d_in, const int* in_sizes, int n_in,
                              void* d_out, int out_size, void* d_ws, size_t ws_size,
                              hipStream_t stream) {
    const float* x_t   = (const float*)d_in[0];
    const float* x_cnn = (const float*)d_in[1];
    const float* Wp  = (const float*)d_in[2];
    const float* bp  = (const float*)d_in[3];
    const float* g1  = (const float*)d_in[4];
    const float* b1  = (const float*)d_in[5];
    const float* rm1 = (const float*)d_in[6];
    const float* rv1 = (const float*)d_in[7];
    const float* Wg  = (const float*)d_in[8];
    const float* bg  = (const float*)d_in[9];
    const float* Wth = (const float*)d_in[10];
    const float* bth = (const float*)d_in[11];
    const float* Wph = (const float*)d_in[12];
    const float* bph = (const float*)d_in[13];
    const float* Wz  = (const float*)d_in[14];
    const float* bz  = (const float*)d_in[15];
    const float* g2  = (const float*)d_in[16];
    const float* b2  = (const float*)d_in[17];
    const float* rm2 = (const float*)d_in[18];
    const float* rv2 = (const float*)d_in[19];
    float* out = (float*)d_out;

    char* ws = (char*)d_ws;
    // region 0: xT bf16 [8][3136][256] then (after k2) f/p bf16 [8][256][3136]
    ushort* xT   = (ushort*)(ws);
    ushort* f_ws = (ushort*)(ws);
    ushort* thT  = (ushort*)(ws + 12845056);      // bf16 [8][3136][128] = 6,422,528
    ushort* gT   = (ushort*)(ws + 19267584);      // bf16 [8][128][3136] = 6,422,528
    ushort* phi  = (ushort*)(ws + 25690112);      // bf16 [8][256][128]  = 524,288
    float*  y_ws = (float*)(ws + 26214400);       // fp32 [8][196][128]  = 802,816
    float*  z_ws = (float*)(ws + 27017216);       // fp32 [8][256][196]  = 1,605,632
    ushort* Wcomb= (ushort*)(ws + 28622848);      // bf16 [256][256]     = 131,072
    ushort* Wp_bf= (ushort*)(ws + 28753920);      // bf16 [256][768]     = 393,216
    ushort* Wph_bf=(ushort*)(ws + 29147136);      // bf16 [128][256]     = 65,536
    ushort* xact = (ushort*)(ws + 29212672);      // bf16 [8*256][256]   = 1,048,576

    kconv_w<<<dim3(256), dim3(256), 0, stream>>>(Wth, Wg, Wp, g1, rv1, Wph, Wcomb, Wp_bf, Wph_bf, y_ws);
    k0_xT<<<dim3(1568), dim3(256), 0, stream>>>(x_cnn, xT);
    k1a_proj<<<dim3(128), dim3(256), 0, stream>>>(x_t, Wp_bf, bp, g1, b1, rm1, rv1, xact);
    k1b_phi<<<dim3(64), dim3(256), 0, stream>>>(xact, Wph_bf, bph, phi);
    k2_mfma<<<dim3(1568), dim3(256), 0, stream>>>(Wcomb, bth, bg, xT, thT, gT);
    k3a_mfma<<<dim3(1568), dim3(256), 0, stream>>>(phi, thT, f_ws);
    k3b_softmax<<<dim3(1568), dim3(256), 0, stream>>>(f_ws);
    k3c_mfma<<<dim3(448), dim3(256), 0, stream>>>(f_ws, gT, y_ws);
    k4a_z<<<dim3(200), dim3(256), 0, stream>>>(y_ws, Wz, bz, g2, b2, rm2, rv2, z_ws);
    k4b_out<<<dim3(6272), dim3(256), 0, stream>>>(x_cnn, z_ws, out);
}

// Round 4
// 94.124 us; speedup vs baseline: 2.7975x; 1.0965x over previous
//
#include <hip/hip_runtime.h>
#include <hip/hip_bf16.h>

// Shapes (fixed): B=8, E=768, C=256, CI=128, H=W=14, UP=4 -> H2=W2=56, N=3136, NQ=196
#define B_ 8
#define E_ 768
#define C_ 256
#define CI_ 128
#define NQ_ 196
#define N_ 3136

typedef short bf16x8 __attribute__((ext_vector_type(8)));
typedef float f32x4 __attribute__((ext_vector_type(4)));

__device__ __forceinline__ ushort f2bf(float x) {
    union { float f; uint u; } v; v.f = x;
    uint r = v.u + 0x7FFFu + ((v.u >> 16) & 1u);   // RNE
    return (ushort)(r >> 16);
}
__device__ __forceinline__ uint pack2(float a, float b) {
    return (uint)f2bf(a) | ((uint)f2bf(b) << 16);
}

// ---------------- kconv: weights -> bf16 (BN1 folded into Wp), zero y/rowsum ---
// grid 256, block 256
__global__ __launch_bounds__(256) void kconv_w(
    const float* __restrict__ Wth, const float* __restrict__ Wg,
    const float* __restrict__ Wp, const float* __restrict__ g1, const float* __restrict__ rv1,
    const float* __restrict__ Wph,
    ushort* __restrict__ Wcomb, ushort* __restrict__ Wp_bf, ushort* __restrict__ Wph_bf,
    float* __restrict__ y_ws, float* __restrict__ rowsum)
{
    int idx = blockIdx.x * 256 + threadIdx.x;     // 0..65535
    int o = idx >> 8, c = idx & 255;
    float v = (o < 128) ? Wth[o * 256 + c] : Wg[(o - 128) * 256 + c];
    Wcomb[idx] = f2bf(v);
    for (int i = idx; i < 196608; i += 65536) {
        int oo = i / 768;
        float inv1 = g1[oo] * rsqrtf(rv1[oo] + 1e-6f);
        Wp_bf[i] = f2bf(Wp[i] * inv1);
    }
    if (idx < 32768) Wph_bf[idx] = f2bf(Wph[idx]);
    if (idx < 2048) rowsum[idx] = 0.0f;
    for (int i = idx; i < B_ * NQ_ * CI_; i += 65536) y_ws[i] = 0.0f;
}

// ---------------- k0: x_cnn [b][c][n] fp32 -> xT [b][n][c] bf16 ----------------
// grid 8*4*49 = 1568, block 256
__global__ __launch_bounds__(256) void k0_xT(
    const float* __restrict__ x_cnn, ushort* __restrict__ xT)
{
    __shared__ float Xs[64][68];
    int bx = blockIdx.x;
    int b = bx & 7; int rest = bx >> 3;
    int ct = rest & 3, nt = rest >> 2;            // ct 0..3, nt 0..48
    int c0 = ct * 64, n0 = nt * 64;
    int t = threadIdx.x;
    #pragma unroll
    for (int rr = 0; rr < 4; ++rr) {
        int idx = t + rr * 256;                   // 0..1023
        int c = idx >> 4, n4 = idx & 15;
        float4 v = *(const float4*)(x_cnn + ((size_t)(b * C_) + c0 + c) * N_ + n0 + n4 * 4);
        *(float4*)(&Xs[c][n4 * 4]) = v;
    }
    __syncthreads();
    int n = t & 63, cc = t >> 6;                  // cc 0..3 (16 c each)
    ushort vals[16];
    #pragma unroll
    for (int j = 0; j < 16; ++j)
        vals[j] = f2bf(Xs[cc * 16 + j][n]);
    ushort* outp = xT + ((size_t)(b * N_) + n0 + n) * 256 + c0 + cc * 16;
    *(uint4*)(outp) = *(const uint4*)(&vals[0]);
    *(uint4*)(outp + 8) = *(const uint4*)(&vals[8]);
}

// ---------------- K1a: xact = relu(BN(x_t @ Wp^T)) via MFMA --------------------
// grid 8*8*4 = 256 (32q x 64c tiles), block 256 (4 waves), K=768, prefetched
__global__ __launch_bounds__(256) void k1a_proj(
    const float* __restrict__ x_t, const ushort* __restrict__ Wp_bf,
    const float* __restrict__ bp, const float* __restrict__ g1, const float* __restrict__ b1,
    const float* __restrict__ rm1, const float* __restrict__ rv1,
    ushort* __restrict__ xact)
{
    __shared__ ushort Al[32 * 40];
    __shared__ ushort Bl[64 * 40];
    int bx = blockIdx.x;
    int b = bx & 7; int rest = bx >> 3;
    int mt = rest & 7, nt = rest >> 3;            // mt 0..7 (32q), nt 0..3 (64c)
    int q0 = mt * 32, c0 = nt * 64;
    int t = threadIdx.x;
    int lane = t & 63, w = t >> 6;

    int arow = t >> 3, ac4 = t & 7;               // A: 32 rows x 32k, float4/thread
    bool arow_ok = (q0 + arow) < NQ_;
    const float* gax = x_t + (size_t)b * 197 * 768 + (size_t)(1 + q0 + arow) * 768 + ac4 * 4;
    int brow = t >> 2, bc = t & 3;                // B: 64 rows x 32k, uint4/thread
    const ushort* gb = Wp_bf + (size_t)(c0 + brow) * 768 + bc * 8;
    ushort* la = &Al[arow * 40 + ac4 * 4];
    ushort* lb = &Bl[brow * 40 + bc * 8];

    f32x4 acc[2];
    acc[0] = (f32x4){0.f, 0.f, 0.f, 0.f};
    acc[1] = (f32x4){0.f, 0.f, 0.f, 0.f};

    int am = (lane & 15) * 40 + (lane >> 4) * 8;
    int bn = (w * 16 + (lane & 15)) * 40 + (lane >> 4) * 8;

    uint2 aw; aw.x = 0; aw.y = 0;
    if (arow_ok) { float4 x0 = *(const float4*)(gax); aw.x = pack2(x0.x, x0.y); aw.y = pack2(x0.z, x0.w); }
    uint4 bw = *(const uint4*)(gb);

    for (int ks = 0; ks < 24; ++ks) {
        __syncthreads();
        *(uint2*)la = aw;
        *(uint4*)lb = bw;
        __syncthreads();
        if (ks + 1 < 24) {
            aw.x = 0; aw.y = 0;
            if (arow_ok) {
                float4 x0 = *(const float4*)(gax + (ks + 1) * 32);
                aw.x = pack2(x0.x, x0.y); aw.y = pack2(x0.z, x0.w);
            }
            bw = *(const uint4*)(gb + (ks + 1) * 32);
        }
        bf16x8 af0 = *(const bf16x8*)(&Al[am]);
        bf16x8 af1 = *(const bf16x8*)(&Al[am + 16 * 40]);
        bf16x8 bfv = *(const bf16x8*)(&Bl[bn]);
        acc[0] = __builtin_amdgcn_mfma_f32_16x16x32_bf16(af0, bfv, acc[0], 0, 0, 0);
        acc[1] = __builtin_amdgcn_mfma_f32_16x16x32_bf16(af1, bfv, acc[1], 0, 0, 0);
    }

    int r4 = (lane >> 4) * 4;
    int cn = lane & 15;
    int c = c0 + w * 16 + cn;
    float inv1 = g1[c] * rsqrtf(rv1[c] + 1e-6f);
    float badd = bp[c] * inv1 + b1[c] - rm1[c] * inv1;
    #pragma unroll
    for (int fm = 0; fm < 2; ++fm) {
        int q = q0 + fm * 16 + r4;
        #pragma unroll
        for (int r = 0; r < 4; ++r) {
            float vv = fmaxf(acc[fm][r] + badd, 0.0f);
            xact[((size_t)((b << 8) + q + r)) * 256 + c] = f2bf(vv);
        }
    }
}

// ---------------- K1b: phi = xact @ Wph^T + bph via MFMA -----------------------
// grid 8*4*2 = 64, block 256, K=256, prefetched
__global__ __launch_bounds__(256) void k1b_phi(
    const ushort* __restrict__ xact, const ushort* __restrict__ Wph_bf,
    const float* __restrict__ bph, ushort* __restrict__ phi_bf)
{
    __shared__ ushort Al[64 * 40];
    __shared__ ushort Bl[64 * 40];
    int bx = blockIdx.x;
    int b = bx & 7; int rest = bx >> 3;
    int mt = rest & 3, nt = rest >> 2;           // nt 0..1
    int q0 = mt * 64, i0 = nt * 64;
    int t = threadIdx.x;
    int lane = t & 63, w = t >> 6;
    int wm = w >> 1, wn = w & 1;
    int row = t >> 2, chunk = t & 3;

    const ushort* ga = xact + ((size_t)((b << 8) + q0 + row)) * 256 + chunk * 8;
    const ushort* gb = Wph_bf + (size_t)(i0 + row) * 256 + chunk * 8;
    ushort* la = &Al[row * 40 + chunk * 8];
    ushort* lb = &Bl[row * 40 + chunk * 8];

    f32x4 acc[2][2];
    #pragma unroll
    for (int a = 0; a < 2; ++a)
        #pragma unroll
        for (int bb = 0; bb < 2; ++bb) acc[a][bb] = (f32x4){0.f, 0.f, 0.f, 0.f};

    int am = (wm * 32 + (lane & 15)) * 40 + (lane >> 4) * 8;
    int bn = (wn * 32 + (lane & 15)) * 40 + (lane >> 4) * 8;

    uint4 aw = *(const uint4*)(ga);
    uint4 bw = *(const uint4*)(gb);
    for (int ks = 0; ks < 8; ++ks) {
        __syncthreads();
        *(uint4*)la = aw;
        *(uint4*)lb = bw;
        __syncthreads();
        if (ks + 1 < 8) {
            aw = *(const uint4*)(ga + (ks + 1) * 32);
            bw = *(const uint4*)(gb + (ks + 1) * 32);
        }
        bf16x8 af[2], bfv[2];
        #pragma unroll
        for (int fm = 0; fm < 2; ++fm) af[fm] = *(const bf16x8*)(&Al[am + fm * 16 * 40]);
        #pragma unroll
        for (int fn = 0; fn < 2; ++fn) bfv[fn] = *(const bf16x8*)(&Bl[bn + fn * 16 * 40]);
        #pragma unroll
        for (int fm = 0; fm < 2; ++fm)
            #pragma unroll
            for (int fn = 0; fn < 2; ++fn)
                acc[fm][fn] = __builtin_amdgcn_mfma_f32_16x16x32_bf16(af[fm], bfv[fn], acc[fm][fn], 0, 0, 0);
    }

    int r4 = (lane >> 4) * 4;
    int cn = lane & 15;
    #pragma unroll
    for (int fn = 0; fn < 2; ++fn) {
        int i = i0 + wn * 32 + fn * 16 + cn;
        float bias = bph[i];
        #pragma unroll
        for (int fm = 0; fm < 2; ++fm) {
            int q = q0 + wm * 32 + fm * 16 + r4;
            #pragma unroll
            for (int r = 0; r < 4; ++r) {
                ushort val = ((q + r) < NQ_) ? f2bf(acc[fm][fn][r] + bias) : (ushort)0;
                phi_bf[((size_t)((b << 8) + q + r)) * 128 + i] = val;
            }
        }
    }
}

// ---------------- K2: MFMA GEMM out[o][n] = Wcomb[o]·xT[n], K=256 --------------
// grid 8*4*49 = 1568, block 256 (4 waves, 64x64 tile), prefetched
__global__ __launch_bounds__(256) void k2_mfma(
    const ushort* __restrict__ Wcomb, const float* __restrict__ bth, const float* __restrict__ bg,
    const ushort* __restrict__ xT, ushort* __restrict__ thT, ushort* __restrict__ gT)
{
    __shared__ ushort Al[64 * 40];
    __shared__ ushort Bl[64 * 40];
    int bx = blockIdx.x;
    int b = bx & 7; int rest = bx >> 3;
    int mt = rest & 3, nt = rest >> 2;
    int o0 = mt * 64, n0 = nt * 64;
    int t = threadIdx.x;
    int lane = t & 63, w = t >> 6;
    int wm = w >> 1, wn = w & 1;
    int row = t >> 2, chunk = t & 3;

    const ushort* ga = Wcomb + (size_t)(o0 + row) * 256 + chunk * 8;
    const ushort* gb = xT + ((size_t)(b * N_) + n0 + row) * 256 + chunk * 8;
    ushort* la = &Al[row * 40 + chunk * 8];
    ushort* lb = &Bl[row * 40 + chunk * 8];

    f32x4 acc[2][2];
    #pragma unroll
    for (int a = 0; a < 2; ++a)
        #pragma unroll
        for (int bb = 0; bb < 2; ++bb) acc[a][bb] = (f32x4){0.f, 0.f, 0.f, 0.f};

    int am = (wm * 32 + (lane & 15)) * 40 + (lane >> 4) * 8;
    int bn = (wn * 32 + (lane & 15)) * 40 + (lane >> 4) * 8;

    uint4 aw = *(const uint4*)(ga);
    uint4 bw = *(const uint4*)(gb);
    for (int ks = 0; ks < 8; ++ks) {
        __syncthreads();
        *(uint4*)la = aw;
        *(uint4*)lb = bw;
        __syncthreads();
        if (ks + 1 < 8) {
            aw = *(const uint4*)(ga + (ks + 1) * 32);
            bw = *(const uint4*)(gb + (ks + 1) * 32);
        }
        bf16x8 af[2], bfv[2];
        #pragma unroll
        for (int fm = 0; fm < 2; ++fm) af[fm] = *(const bf16x8*)(&Al[am + fm * 16 * 40]);
        #pragma unroll
        for (int fn = 0; fn < 2; ++fn) bfv[fn] = *(const bf16x8*)(&Bl[bn + fn * 16 * 40]);
        #pragma unroll
        for (int fm = 0; fm < 2; ++fm)
            #pragma unroll
            for (int fn = 0; fn < 2; ++fn)
                acc[fm][fn] = __builtin_amdgcn_mfma_f32_16x16x32_bf16(af[fm], bfv[fn], acc[fm][fn], 0, 0, 0);
    }

    int r4 = (lane >> 4) * 4;
    int cn = lane & 15;
    #pragma unroll
    for (int fm = 0; fm < 2; ++fm) {
        int ob = o0 + wm * 32 + fm * 16 + r4;
        #pragma unroll
        for (int fn = 0; fn < 2; ++fn) {
            int n = n0 + wn * 32 + fn * 16 + cn;
            if (ob < 128) {
                ushort4 v;
                v.x = f2bf(acc[fm][fn][0] + bth[ob + 0]);
                v.y = f2bf(acc[fm][fn][1] + bth[ob + 1]);
                v.z = f2bf(acc[fm][fn][2] + bth[ob + 2]);
                v.w = f2bf(acc[fm][fn][3] + bth[ob + 3]);
                *(ushort4*)(&thT[((size_t)(b * N_) + n) * 128 + ob]) = v;
            } else {
                int og = ob - 128;
                #pragma unroll
                for (int r = 0; r < 4; ++r)
                    gT[((size_t)(b * 128) + og + r) * N_ + n] = f2bf(acc[fm][fn][r] + bg[og + r]);
            }
        }
    }
}

// ---------------- K3a: ef[q][n] = exp(phi[q]·thetaT[n]); rowsum atomics --------
// grid 8*4*49 = 1568, block 256, K=128, prefetched, fused exp + row-sum
__global__ __launch_bounds__(256) void k3a_fused(
    const ushort* __restrict__ phi_bf, const ushort* __restrict__ thT,
    ushort* __restrict__ ef, float* __restrict__ rowsum)
{
    __shared__ ushort Al[64 * 40];
    __shared__ ushort Bl[64 * 40];
    __shared__ float sums[2][64];
    int bx = blockIdx.x;
    int b = bx & 7; int rest = bx >> 3;
    int mt = rest & 3, nt = rest >> 2;
    int q0 = mt * 64, n0 = nt * 64;
    int t = threadIdx.x;
    int lane = t & 63, w = t >> 6;
    int wm = w >> 1, wn = w & 1;
    int row = t >> 2, chunk = t & 3;

    const ushort* ga = phi_bf + ((size_t)((b << 8) + q0 + row)) * 128 + chunk * 8;
    const ushort* gb = thT + ((size_t)(b * N_) + n0 + row) * 128 + chunk * 8;
    ushort* la = &Al[row * 40 + chunk * 8];
    ushort* lb = &Bl[row * 40 + chunk * 8];

    f32x4 acc[2][2];
    #pragma unroll
    for (int a = 0; a < 2; ++a)
        #pragma unroll
        for (int bb = 0; bb < 2; ++bb) acc[a][bb] = (f32x4){0.f, 0.f, 0.f, 0.f};

    int am = (wm * 32 + (lane & 15)) * 40 + (lane >> 4) * 8;
    int bn = (wn * 32 + (lane & 15)) * 40 + (lane >> 4) * 8;

    uint4 aw = *(const uint4*)(ga);
    uint4 bw = *(const uint4*)(gb);
    #pragma unroll
    for (int ks = 0; ks < 4; ++ks) {
        __syncthreads();
        *(uint4*)la = aw;
        *(uint4*)lb = bw;
        __syncthreads();
        if (ks + 1 < 4) {
            aw = *(const uint4*)(ga + (ks + 1) * 32);
            bw = *(const uint4*)(gb + (ks + 1) * 32);
        }
        bf16x8 af[2], bfv[2];
        #pragma unroll
        for (int fm = 0; fm < 2; ++fm) af[fm] = *(const bf16x8*)(&Al[am + fm * 16 * 40]);
        #pragma unroll
        for (int fn = 0; fn < 2; ++fn) bfv[fn] = *(const bf16x8*)(&Bl[bn + fn * 16 * 40]);
        #pragma unroll
        for (int fm = 0; fm < 2; ++fm)
            #pragma unroll
            for (int fn = 0; fn < 2; ++fn)
                acc[fm][fn] = __builtin_amdgcn_mfma_f32_16x16x32_bf16(af[fm], bfv[fn], acc[fm][fn], 0, 0, 0);
    }

    int r4 = (lane >> 4) * 4;
    int cn = lane & 15;
    float rs[2][4] = {{0, 0, 0, 0}, {0, 0, 0, 0}};
    #pragma unroll
    for (int fm = 0; fm < 2; ++fm) {
        int qb = q0 + wm * 32 + fm * 16 + r4;
        #pragma unroll
        for (int fn = 0; fn < 2; ++fn) {
            int n = n0 + wn * 32 + fn * 16 + cn;
            #pragma unroll
            for (int r = 0; r < 4; ++r) {
                float e = __expf(acc[fm][fn][r]);
                rs[fm][r] += e;
                ef[((size_t)((b << 8) + qb + r)) * N_ + n] = f2bf(e);
            }
        }
    }
    // reduce rs over the 16 lanes of each row-group (lane bits 0..3)
    #pragma unroll
    for (int off = 1; off <= 8; off <<= 1) {
        #pragma unroll
        for (int fm = 0; fm < 2; ++fm)
            #pragma unroll
            for (int r = 0; r < 4; ++r)
                rs[fm][r] += __shfl_xor(rs[fm][r], off);
    }
    if (cn == 0) {
        #pragma unroll
        for (int fm = 0; fm < 2; ++fm)
            #pragma unroll
            for (int r = 0; r < 4; ++r)
                sums[wn][wm * 32 + fm * 16 + r4 + r] = rs[fm][r];
    }
    __syncthreads();
    if (t < 64)
        atomicAdd(&rowsum[(b << 8) + q0 + t], sums[0][t] + sums[1][t]);
}

// ---------------- K3c: y[q][i] = (1/rowsum)·Σ ef[q][n]·gT[i][n], K-split 7 ------
// grid 8*4*7 = 224, block 256, tile 64q x 128i, prefetched, atomicAdd into y
__global__ __launch_bounds__(256) void k3c_fused(
    const ushort* __restrict__ ef, const ushort* __restrict__ gT,
    const float* __restrict__ rowsum, float* __restrict__ y_ws)
{
    __shared__ ushort Al[64 * 40];
    __shared__ ushort Bl[128 * 40];
    __shared__ float invs[64];
    int bx = blockIdx.x;
    int b = bx & 7; int rest = bx >> 3;          // 0..27
    int qt = rest & 3, ksp = rest >> 2;          // qt 0..3, ksp 0..6
    int q0 = qt * 64, kbase = ksp * 448;
    int t = threadIdx.x;
    int lane = t & 63, w = t >> 6;
    int wm = w >> 1, wn = w & 1;

    if (t < 64) invs[t] = 1.0f / rowsum[(b << 8) + q0 + t];

    int arow = t >> 2, achunk = t & 3;
    const ushort* ga = ef + ((size_t)((b << 8) + q0 + arow)) * N_ + kbase + achunk * 8;
    const ushort* gb0 = gT + ((size_t)(b * 128) + arow) * N_ + kbase + achunk * 8;
    const ushort* gb1 = gb0 + (size_t)64 * N_;
    ushort* la = &Al[arow * 40 + achunk * 8];
    ushort* lb0 = &Bl[arow * 40 + achunk * 8];
    ushort* lb1 = lb0 + 64 * 40;

    f32x4 acc[2][4];
    #pragma unroll
    for (int a = 0; a < 2; ++a)
        #pragma unroll
        for (int bb = 0; bb < 4; ++bb) acc[a][bb] = (f32x4){0.f, 0.f, 0.f, 0.f};

    int am = (wm * 32 + (lane & 15)) * 40 + (lane >> 4) * 8;
    int bn = (wn * 64 + (lane & 15)) * 40 + (lane >> 4) * 8;

    uint4 aw = *(const uint4*)(ga);
    uint4 bw0 = *(const uint4*)(gb0);
    uint4 bw1 = *(const uint4*)(gb1);
    for (int ks = 0; ks < 14; ++ks) {
        __syncthreads();
        *(uint4*)la = aw;
        *(uint4*)lb0 = bw0;
        *(uint4*)lb1 = bw1;
        __syncthreads();
        if (ks + 1 < 14) {
            aw = *(const uint4*)(ga + (ks + 1) * 32);
            bw0 = *(const uint4*)(gb0 + (ks + 1) * 32);
            bw1 = *(const uint4*)(gb1 + (ks + 1) * 32);
        }
        bf16x8 af[2], bfv[4];
        #pragma unroll
        for (int fm = 0; fm < 2; ++fm) af[fm] = *(const bf16x8*)(&Al[am + fm * 16 * 40]);
        #pragma unroll
        for (int fn = 0; fn < 4; ++fn) bfv[fn] = *(const bf16x8*)(&Bl[bn + fn * 16 * 40]);
        #pragma unroll
        for (int fm = 0; fm < 2; ++fm)
            #pragma unroll
            for (int fn = 0; fn < 4; ++fn)
                acc[fm][fn] = __builtin_amdgcn_mfma_f32_16x16x32_bf16(af[fm], bfv[fn], acc[fm][fn], 0, 0, 0);
    }

    int r4 = (lane >> 4) * 4;
    int cn = lane & 15;
    #pragma unroll
    for (int fm = 0; fm < 2; ++fm) {
        int ql = wm * 32 + fm * 16 + r4;
        #pragma unroll
        for (int fn = 0; fn < 4; ++fn) {
            int i = wn * 64 + fn * 16 + cn;
            #pragma unroll
            for (int r = 0; r < 4; ++r) {
                int q = q0 + ql + r;
                if (q < NQ_)
                    atomicAdd(&y_ws[((size_t)(b * NQ_) + q) * 128 + i],
                              acc[fm][fn][r] * invs[ql + r]);
            }
        }
    }
}

// ---------------- K4a: z = BN2(Wz @ y + bz) on 196-grid -------------------------
// grid: B*25, block 256
__global__ __launch_bounds__(256) void k4a_z(
    const float* __restrict__ y_ws, const float* __restrict__ Wz, const float* __restrict__ bz,
    const float* __restrict__ g2, const float* __restrict__ b2,
    const float* __restrict__ rm2, const float* __restrict__ rv2,
    float* __restrict__ z_ws)
{
    __shared__ float ys[8][128];
    int bx = blockIdx.x;
    int b = bx / 25, qt = bx % 25;
    int q0 = qt * 8;
    int t = threadIdx.x;
    #pragma unroll
    for (int rr = 0; rr < 4; ++rr) {
        int idx = t + rr * 256;
        int p = idx >> 7, ii = idx & 127;
        int q = q0 + p;
        ys[p][ii] = (q < NQ_) ? y_ws[(size_t)b * NQ_ * CI_ + (size_t)q * CI_ + ii] : 0.0f;
    }
    __syncthreads();
    int c = t;
    float acc[8] = {0, 0, 0, 0, 0, 0, 0, 0};
    const float* wrow = Wz + (size_t)c * 128;
    for (int i4 = 0; i4 < 32; ++i4) {
        float4 w = *(const float4*)(wrow + i4 * 4);
        #pragma unroll
        for (int p = 0; p < 8; ++p) {
            float4 yv = *(const float4*)(&ys[p][i4 * 4]);
            acc[p] += w.x * yv.x + w.y * yv.y + w.z * yv.z + w.w * yv.w;
        }
    }
    float inv2 = g2[c] * rsqrtf(rv2[c] + 1e-5f);
    float add2 = b2[c] - rm2[c] * inv2;
    float bzc = bz[c];
    #pragma unroll
    for (int p = 0; p < 8; ++p) {
        int q = q0 + p;
        if (q < NQ_)
            z_ws[(size_t)b * C_ * NQ_ + (size_t)c * NQ_ + q] = (acc[p] + bzc) * inv2 + add2;
    }
}

// ---------------- K4b: out = upsample(z) + x_cnn --------------------------------
// grid 6272, block 256, one float4 per thread
__global__ __launch_bounds__(256) void k4b_out(
    const float* __restrict__ x_cnn, const float* __restrict__ z_ws, float* __restrict__ out)
{
    int idx = blockIdx.x * 256 + threadIdx.x;   // float4 index over (B,C,56,14)
    int w4 = idx % 14;
    int rest = idx / 14;
    int h = rest % 56;
    rest /= 56;
    int c = rest % 256;
    int b = rest / 256;
    int q = (h >> 2) * 14 + w4;
    float z = z_ws[((size_t)b * C_ + c) * NQ_ + q];
    float4 xv = *(const float4*)(x_cnn + (size_t)idx * 4);
    float4 o = make_float4(xv.x + z, xv.y + z, xv.z + z, xv.w + z);
    *(float4*)(out + (size_t)idx * 4) = o;
}

extern "C" void kernel_launch(void* const* d_in, const int* in_sizes, int n_in,
                              void* d_out, int out_size, void* d_ws, size_t ws_size,
                              hipStream_t stream) {
    const float* x_t   = (const float*)d_in[0];
    const float* x_cnn = (const float*)d_in[1];
    const float* Wp  = (const float*)d_in[2];
    const float* bp  = (const float*)d_in[3];
    const float* g1  = (const float*)d_in[4];
    const float* b1  = (const float*)d_in[5];
    const float* rm1 = (const float*)d_in[6];
    const float* rv1 = (const float*)d_in[7];
    const float* Wg  = (const float*)d_in[8];
    const float* bg  = (const float*)d_in[9];
    const float* Wth = (const float*)d_in[10];
    const float* bth = (const float*)d_in[11];
    const float* Wph = (const float*)d_in[12];
    const float* bph = (const float*)d_in[13];
    const float* Wz  = (const float*)d_in[14];
    const float* bz  = (const float*)d_in[15];
    const float* g2  = (const float*)d_in[16];
    const float* b2  = (const float*)d_in[17];
    const float* rm2 = (const float*)d_in[18];
    const float* rv2 = (const float*)d_in[19];
    float* out = (float*)d_out;

    char* ws = (char*)d_ws;
    // region 0: xT bf16 [8][3136][256] then (after k2 done) ef bf16 [8][256][3136]
    ushort* xT   = (ushort*)(ws);
    ushort* f_ws = (ushort*)(ws);
    ushort* thT  = (ushort*)(ws + 12845056);      // bf16 [8][3136][128] = 6,422,528
    ushort* gT   = (ushort*)(ws + 19267584);      // bf16 [8][128][3136] = 6,422,528
    ushort* phi  = (ushort*)(ws + 25690112);      // bf16 [8][256][128]  = 524,288
    float*  y_ws = (float*)(ws + 26214400);       // fp32 [8][196][128]  = 802,816
    float*  z_ws = (float*)(ws + 27017216);       // fp32 [8][256][196]  = 1,605,632
    ushort* Wcomb= (ushort*)(ws + 28622848);      // bf16 [256][256]     = 131,072
    ushort* Wp_bf= (ushort*)(ws + 28753920);      // bf16 [256][768]     = 393,216
    ushort* Wph_bf=(ushort*)(ws + 29147136);      // bf16 [128][256]     = 65,536
    ushort* xact = (ushort*)(ws + 29212672);      // bf16 [8*256][256]   = 1,048,576
    float*  rowsum=(float*)(ws + 30261248);       // fp32 [8*256]        = 8,192

    kconv_w<<<dim3(256), dim3(256), 0, stream>>>(Wth, Wg, Wp, g1, rv1, Wph, Wcomb, Wp_bf, Wph_bf, y_ws, rowsum);
    k0_xT<<<dim3(1568), dim3(256), 0, stream>>>(x_cnn, xT);
    k1a_proj<<<dim3(256), dim3(256), 0, stream>>>(x_t, Wp_bf, bp, g1, b1, rm1, rv1, xact);
    k1b_phi<<<dim3(64), dim3(256), 0, stream>>>(xact, Wph_bf, bph, phi);
    k2_mfma<<<dim3(1568), dim3(256), 0, stream>>>(Wcomb, bth, bg, xT, thT, gT);
    k3a_fused<<<dim3(1568), dim3(256), 0, stream>>>(phi, thT, f_ws, rowsum);
    k3c_fused<<<dim3(224), dim3(256), 0, stream>>>(f_ws, gT, rowsum, y_ws);
    k4a_z<<<dim3(200), dim3(256), 0, stream>>>(y_ws, Wz, bz, g2, b2, rm2, rv2, z_ws);
    k4b_out<<<dim3(6272), dim3(256), 0, stream>>>(x_cnn, z_ws, out);
}